// Round 1
// baseline (2034.530 us; speedup 1.0000x reference)
//
#include <hip/hip_runtime.h>
#include <cmath>

#define B_ 2
#define S_ 2048
#define E_ 1024
#define H_ 16
#define D_ 64
#define M_ (B_*S_)    // 4096
#define N3_ (3*E_)    // 3072

// ---------------------------------------------------------------------------
// Tiled fp32 GEMM: C[M,N] = A[M,K] @ B[K,N] + bias[N]
// 128x128 block tile, K-tile 16, 256 threads, 8x8 per-thread micro-tile.
// ---------------------------------------------------------------------------
__global__ __launch_bounds__(256)
void gemm_f32_bias(const float* __restrict__ A, const float* __restrict__ Bm,
                   const float* __restrict__ bias, float* __restrict__ C,
                   int M, int N, int K)
{
    __shared__ float As[16][128 + 4];   // [k][m] (A tile transposed)
    __shared__ float Bs[16][128 + 4];   // [k][n]
    const int tid = threadIdx.x;
    const int bm = blockIdx.y * 128;
    const int bn = blockIdx.x * 128;
    const int tx = tid & 15, ty = tid >> 4;
    float acc[8][8] = {};

    for (int k0 = 0; k0 < K; k0 += 16) {
        // ---- stage tiles ----
        #pragma unroll
        for (int u = 0; u < 2; u++) {
            int f = tid + u * 256;
            // A: 128 rows x 16 cols = 512 float4
            int r  = f >> 2;
            int k4 = (f & 3) << 2;
            float4 a4 = *(const float4*)(A + (size_t)(bm + r) * K + k0 + k4);
            As[k4 + 0][r] = a4.x; As[k4 + 1][r] = a4.y;
            As[k4 + 2][r] = a4.z; As[k4 + 3][r] = a4.w;
            // B: 16 rows x 128 cols = 512 float4
            int rb = f >> 5;
            int c4 = (f & 31) << 2;
            float4 b4 = *(const float4*)(Bm + (size_t)(k0 + rb) * N + bn + c4);
            *(float4*)&Bs[rb][c4] = b4;
        }
        __syncthreads();
        // ---- compute ----
        #pragma unroll
        for (int kk = 0; kk < 16; kk++) {
            float a[8], b[8];
            *(float4*)&a[0] = *(const float4*)&As[kk][ty * 8];
            *(float4*)&a[4] = *(const float4*)&As[kk][ty * 8 + 4];
            *(float4*)&b[0] = *(const float4*)&Bs[kk][tx * 8];
            *(float4*)&b[4] = *(const float4*)&Bs[kk][tx * 8 + 4];
            #pragma unroll
            for (int i = 0; i < 8; i++)
                #pragma unroll
                for (int j = 0; j < 8; j++)
                    acc[i][j] = fmaf(a[i], b[j], acc[i][j]);
        }
        __syncthreads();
    }
    // ---- epilogue ----
    #pragma unroll
    for (int i = 0; i < 8; i++) {
        int row = bm + ty * 8 + i;
        #pragma unroll
        for (int j4 = 0; j4 < 2; j4++) {
            int c = bn + tx * 8 + j4 * 4;
            float4 o;
            o.x = acc[i][j4 * 4 + 0] + bias[c + 0];
            o.y = acc[i][j4 * 4 + 1] + bias[c + 1];
            o.z = acc[i][j4 * 4 + 2] + bias[c + 2];
            o.w = acc[i][j4 * 4 + 3] + bias[c + 3];
            *(float4*)(C + (size_t)row * N + c) = o;
        }
    }
}

// ---------------------------------------------------------------------------
// Normalized FWHT over 64 lanes via shuffle butterflies (lane = element idx).
// ---------------------------------------------------------------------------
__device__ inline float fwht64(float x, int lane)
{
    #pragma unroll
    for (int h = 1; h < 64; h <<= 1) {
        float y = __shfl_xor(x, h, 64);
        x = (lane & h) ? (y - x) : (x + y);
    }
    return x * 0.125f;   // 1/sqrt(64)
}

// Split qkv -> transformed q,k and v in (b,H,s,D) layout. One wave per (b,s,h).
__global__ __launch_bounds__(256)
void transform_split(const float* __restrict__ qkv, const float* __restrict__ diag,
                     const float* __restrict__ alphap, const float* __restrict__ biasp,
                     float* __restrict__ qT, float* __restrict__ kT, float* __restrict__ vT)
{
    const int lane = threadIdx.x & 63;
    const int w = (blockIdx.x * 256 + threadIdx.x) >> 6;   // 0 .. B*S*H-1
    const int h = w & (H_ - 1);
    const int s = (w >> 4) & (S_ - 1);
    const int b = w >> 15;                                  // / (S_*H_)
    const float alpha = alphap[0];
    const float dg = diag[lane];
    const float bh = biasp[lane];
    const float* row = qkv + (size_t)(b * S_ + s) * N3_;
    const size_t o = ((size_t)((b * H_ + h) * S_) + s) * 64 + lane;

    float xq = row[h * 64 + lane];
    float t  = fwht64(fwht64(xq, lane) * dg, lane);
    qT[o] = xq + alpha * t + bh;

    float xk = row[E_ + h * 64 + lane];
    t = fwht64(fwht64(xk, lane) * dg, lane);
    kT[o] = xk + alpha * t + bh;

    vT[o] = row[2 * E_ + h * 64 + lane];
}

// ---------------------------------------------------------------------------
// Flash attention (fp32): per block: 64 q-rows of one (b,h); iterate 64-key
// tiles with online softmax. 256 threads, 4x4 micro-tiles.
// ---------------------------------------------------------------------------
__global__ __launch_bounds__(256)
void flash_attn(const float* __restrict__ qT, const float* __restrict__ kT,
                const float* __restrict__ vT, const int* __restrict__ mask,
                float* __restrict__ attn /* (b,s,H,D) */)
{
    __shared__ float Qs[64][68];   // [d][r]
    __shared__ float Ks[64][68];   // [d][c]
    __shared__ float Vs[64][68];   // [j][dc]
    __shared__ float Ps[64][68];   // [c][r]
    const int tid = threadIdx.x;
    const int bh = blockIdx.y;
    const int b = bh >> 4, h = bh & 15;
    const int q0 = blockIdx.x * 64;
    const int tx = tid & 15, ty = tid >> 4;
    const float* qb = qT + (size_t)bh * S_ * 64;
    const float* kb = kT + (size_t)bh * S_ * 64;
    const float* vb = vT + (size_t)bh * S_ * 64;

    {   // load Q tile transposed
        int r = tid >> 2, c0 = (tid & 3) << 4;
        const float* src = qb + (size_t)(q0 + r) * 64 + c0;
        #pragma unroll
        for (int i = 0; i < 4; i++) {
            float4 v4 = *(const float4*)(src + i * 4);
            int c = c0 + i * 4;
            Qs[c + 0][r] = v4.x; Qs[c + 1][r] = v4.y;
            Qs[c + 2][r] = v4.z; Qs[c + 3][r] = v4.w;
        }
    }
    float m_i[4], l_i[4], acc[4][4] = {};
    #pragma unroll
    for (int i = 0; i < 4; i++) { m_i[i] = -INFINITY; l_i[i] = 0.f; }
    __syncthreads();

    for (int t = 0; t < S_ / 64; t++) {
        const int k0 = t * 64;
        {   // load K (transposed) and V (row-major) tiles
            int r = tid >> 2, c0 = (tid & 3) << 4;
            const float* ks = kb + (size_t)(k0 + r) * 64 + c0;
            const float* vs = vb + (size_t)(k0 + r) * 64 + c0;
            #pragma unroll
            for (int i = 0; i < 4; i++) {
                float4 v4 = *(const float4*)(ks + i * 4);
                int c = c0 + i * 4;
                Ks[c + 0][r] = v4.x; Ks[c + 1][r] = v4.y;
                Ks[c + 2][r] = v4.z; Ks[c + 3][r] = v4.w;
            }
            #pragma unroll
            for (int i = 0; i < 4; i++)
                *(float4*)&Vs[r][c0 + i * 4] = *(const float4*)(vs + i * 4);
        }
        __syncthreads();

        // S = Q @ K^T
        float sv[4][4] = {};
        #pragma unroll
        for (int d = 0; d < 64; d++) {
            float a[4], bb[4];
            *(float4*)a  = *(const float4*)&Qs[d][ty * 4];
            *(float4*)bb = *(const float4*)&Ks[d][tx * 4];
            #pragma unroll
            for (int i = 0; i < 4; i++)
                #pragma unroll
                for (int j = 0; j < 4; j++)
                    sv[i][j] = fmaf(a[i], bb[j], sv[i][j]);
        }
        // scale + mask
        bool mk[4];
        #pragma unroll
        for (int j = 0; j < 4; j++) mk[j] = mask[b * S_ + k0 + tx * 4 + j] != 0;
        #pragma unroll
        for (int i = 0; i < 4; i++)
            #pragma unroll
            for (int j = 0; j < 4; j++)
                sv[i][j] = mk[j] ? sv[i][j] * 0.125f : -INFINITY;

        // row max over 16 tx-lanes
        float rmax[4], rsum[4], fsc[4], p[4][4];
        #pragma unroll
        for (int i = 0; i < 4; i++)
            rmax[i] = fmaxf(fmaxf(sv[i][0], sv[i][1]), fmaxf(sv[i][2], sv[i][3]));
        #pragma unroll
        for (int mm = 1; mm < 16; mm <<= 1)
            #pragma unroll
            for (int i = 0; i < 4; i++)
                rmax[i] = fmaxf(rmax[i], __shfl_xor(rmax[i], mm, 64));

        #pragma unroll
        for (int i = 0; i < 4; i++) {
            float mn = fmaxf(m_i[i], rmax[i]);
            if (mn == -INFINITY) {        // fully-masked row so far
                fsc[i] = 1.f;
                #pragma unroll
                for (int j = 0; j < 4; j++) p[i][j] = 0.f;
                rsum[i] = 0.f;
            } else {
                fsc[i] = __expf(m_i[i] - mn);   // m_i=-inf -> 0
                #pragma unroll
                for (int j = 0; j < 4; j++) p[i][j] = __expf(sv[i][j] - mn);
                rsum[i] = (p[i][0] + p[i][1]) + (p[i][2] + p[i][3]);
            }
            m_i[i] = mn;
        }
        #pragma unroll
        for (int mm = 1; mm < 16; mm <<= 1)
            #pragma unroll
            for (int i = 0; i < 4; i++)
                rsum[i] += __shfl_xor(rsum[i], mm, 64);
        #pragma unroll
        for (int i = 0; i < 4; i++) {
            l_i[i] = l_i[i] * fsc[i] + rsum[i];
            #pragma unroll
            for (int j = 0; j < 4; j++) acc[i][j] *= fsc[i];
        }
        // stash P transposed for PV
        #pragma unroll
        for (int i = 0; i < 4; i++)
            #pragma unroll
            for (int j = 0; j < 4; j++)
                Ps[tx * 4 + j][ty * 4 + i] = p[i][j];
        __syncthreads();

        // O += P @ V
        #pragma unroll
        for (int j = 0; j < 64; j++) {
            float a[4], bb[4];
            *(float4*)a  = *(const float4*)&Ps[j][ty * 4];
            *(float4*)bb = *(const float4*)&Vs[j][tx * 4];
            #pragma unroll
            for (int i = 0; i < 4; i++)
                #pragma unroll
                for (int c = 0; c < 4; c++)
                    acc[i][c] = fmaf(a[i], bb[c], acc[i][c]);
        }
        __syncthreads();
    }

    // epilogue: normalize and write (b,s,H,D)
    #pragma unroll
    for (int i = 0; i < 4; i++) {
        float inv = l_i[i] > 0.f ? 1.f / l_i[i] : 0.f;
        int sg = q0 + ty * 4 + i;
        float4 o;
        o.x = acc[i][0] * inv; o.y = acc[i][1] * inv;
        o.z = acc[i][2] * inv; o.w = acc[i][3] * inv;
        *(float4*)(attn + ((size_t)(b * S_ + sg) * H_ + h) * 64 + tx * 4) = o;
    }
}

// ---------------------------------------------------------------------------
extern "C" void kernel_launch(void* const* d_in, const int* in_sizes, int n_in,
                              void* d_out, int out_size, void* d_ws, size_t ws_size,
                              hipStream_t stream)
{
    (void)in_sizes; (void)n_in; (void)out_size; (void)ws_size;
    const float* x     = (const float*)d_in[0];
    const int*   mask  = (const int*)  d_in[1];
    const float* Wqkv  = (const float*)d_in[2];
    const float* bqkv  = (const float*)d_in[3];
    const float* Wout  = (const float*)d_in[4];
    const float* bout  = (const float*)d_in[5];
    const float* diag  = (const float*)d_in[6];
    const float* alpha = (const float*)d_in[7];
    const float* biash = (const float*)d_in[8];
    float* out = (float*)d_out;

    float* ws  = (float*)d_ws;
    float* qkv = ws;                                    // M_*N3_   = 12.58M floats
    float* qT  = qkv + (size_t)M_ * N3_;                // B*H*S*D  =  4.19M
    float* kT  = qT  + (size_t)B_ * H_ * S_ * 64;
    float* vT  = kT  + (size_t)B_ * H_ * S_ * 64;
    float* attn = qkv;                                  // qkv dead after transform

    // 1) qkv = x @ Wqkv + bqkv
    gemm_f32_bias<<<dim3(N3_ / 128, M_ / 128), 256, 0, stream>>>(
        x, Wqkv, bqkv, qkv, M_, N3_, E_);
    // 2) per-head transform of q,k; split into (b,H,s,D)
    transform_split<<<(B_ * S_ * H_ * 64) / 256, 256, 0, stream>>>(
        qkv, diag, alpha, biash, qT, kT, vT);
    // 3) flash attention
    flash_attn<<<dim3(S_ / 64, B_ * H_), 256, 0, stream>>>(
        qT, kT, vT, mask, attn);
    // 4) out = attn @ Wout + bout
    gemm_f32_bias<<<dim3(E_ / 128, M_ / 128), 256, 0, stream>>>(
        attn, Wout, bout, out, M_, E_, E_);
}

// Round 2
// 463.193 us; speedup vs baseline: 4.3924x; 4.3924x over previous
//
#include <hip/hip_runtime.h>
#include <cmath>

#define B_ 2
#define S_ 2048
#define E_ 1024
#define H_ 16
#define M_ (B_*S_)    // 4096
#define N3_ (3*E_)    // 3072

typedef unsigned short u16;
typedef __attribute__((ext_vector_type(8))) short bf16x8;   // 8 bf16 = 4 VGPRs
typedef __attribute__((ext_vector_type(4))) float f32x4;

// fp32 -> bf16 round-to-nearest-even
__device__ __forceinline__ u16 f2bf(float x) {
    unsigned u = __float_as_uint(x);
    return (u16)((u + 0x7FFFu + ((u >> 16) & 1u)) >> 16);
}
__device__ __forceinline__ void gld_lds16(const void* g, void* l) {
    __builtin_amdgcn_global_load_lds((const __attribute__((address_space(1))) void*)g,
                                     (__attribute__((address_space(3))) void*)l, 16, 0, 0);
}

// ---------------------------------------------------------------------------
// Elementwise split: in (f32, n4*4 elems) -> hi/lo bf16 arrays (same layout).
// ---------------------------------------------------------------------------
__global__ __launch_bounds__(256)
void split_a(const float* __restrict__ in, u16* __restrict__ hi, u16* __restrict__ lo, int n4)
{
    int i = blockIdx.x * 256 + threadIdx.x;
    if (i >= n4) return;
    float4 v = ((const float4*)in)[i];
    float vv[4] = {v.x, v.y, v.z, v.w};
    unsigned hp[2], lp[2];
    u16 h[4], l[4];
    #pragma unroll
    for (int j = 0; j < 4; j++) {
        h[j] = f2bf(vv[j]);
        float hf = __uint_as_float((unsigned)h[j] << 16);
        l[j] = f2bf(vv[j] - hf);
    }
    hp[0] = (unsigned)h[0] | ((unsigned)h[1] << 16);
    hp[1] = (unsigned)h[2] | ((unsigned)h[3] << 16);
    lp[0] = (unsigned)l[0] | ((unsigned)l[1] << 16);
    lp[1] = (unsigned)l[2] | ((unsigned)l[3] << 16);
    ((uint2*)hi)[i] = make_uint2(hp[0], hp[1]);
    ((uint2*)lo)[i] = make_uint2(lp[0], lp[1]);
}

// ---------------------------------------------------------------------------
// Transpose+split: W [K][N] f32 -> Bt_hi/lo [N][K] bf16 (B^T for GEMM B-frags).
// ---------------------------------------------------------------------------
__global__ __launch_bounds__(256)
void split_bt(const float* __restrict__ W, u16* __restrict__ hi, u16* __restrict__ lo,
              int K, int N)
{
    int idx = blockIdx.x * 256 + threadIdx.x;
    if (idx >= K * N) return;
    int k = idx / N, nn = idx - k * N;
    float v = W[idx];
    u16 h = f2bf(v);
    float hf = __uint_as_float((unsigned)h << 16);
    u16 l = f2bf(v - hf);
    size_t o = (size_t)nn * K + k;
    hi[o] = h; lo[o] = l;
}

// ---------------------------------------------------------------------------
// Split-bf16 3-term GEMM: C[M][N] f32 = Ah@Bh + Al@Bh + Ah@Bl + bias
// A*: [M][K] bf16 row-major. B*: B^T = [N][K] bf16 row-major.
// 128x128 tile, BK=64, 4 waves (2x2), 64x64 per wave, mfma 16x16x32 bf16.
// ---------------------------------------------------------------------------
__global__ __launch_bounds__(256)
void gemm3(const u16* __restrict__ Ahi, const u16* __restrict__ Alo,
           const u16* __restrict__ Bhi, const u16* __restrict__ Blo,
           const float* __restrict__ bias, float* __restrict__ C,
           int M, int N, int K)
{
    __shared__ u16 As[128*64];   // [m][k] linear
    __shared__ u16 Bs[128*64];   // [n][k] linear
    const int tid = threadIdx.x;
    const int lane = tid & 63;
    const int w = tid >> 6;
    const int wr = w >> 1, wc = w & 1;
    const int l15 = lane & 15, g = lane >> 4;
    const int bm = blockIdx.y * 128;
    const int bn = blockIdx.x * 128;
    const f32x4 z4 = {0.f, 0.f, 0.f, 0.f};
    f32x4 acc[4][4];
    #pragma unroll
    for (int m = 0; m < 4; m++)
        #pragma unroll
        for (int n = 0; n < 4; n++) acc[m][n] = z4;

    const int niter = 3 * K / 64;
    for (int i = 0; i < niter; i++) {
        int kb = i * 64;
        const u16* Ab; const u16* Bb; int ko;
        if (kb < K)          { Ab = Ahi; Bb = Bhi; ko = kb; }
        else if (kb < 2 * K) { Ab = Alo; Bb = Bhi; ko = kb - K; }
        else                 { Ab = Ahi; Bb = Blo; ko = kb - 2 * K; }
        __syncthreads();
        #pragma unroll
        for (int u = 0; u < 4; u++) {
            int f = u * 256 + tid;                       // 1024 chunks of 16B per tile
            gld_lds16(Ab + (size_t)(bm + (f >> 3)) * K + ko + (f & 7) * 8,
                      (char*)As + ((f >> 6) << 10));
            gld_lds16(Bb + (size_t)(bn + (f >> 3)) * K + ko + (f & 7) * 8,
                      (char*)Bs + ((f >> 6) << 10));
        }
        __syncthreads();
        #pragma unroll
        for (int kc = 0; kc < 2; kc++) {
            bf16x8 a[4], bfr[4];
            #pragma unroll
            for (int m = 0; m < 4; m++)
                a[m] = *(const bf16x8*)&As[(wr*64 + m*16 + l15)*64 + kc*32 + g*8];
            #pragma unroll
            for (int n = 0; n < 4; n++)
                bfr[n] = *(const bf16x8*)&Bs[(wc*64 + n*16 + l15)*64 + kc*32 + g*8];
            #pragma unroll
            for (int m = 0; m < 4; m++)
                #pragma unroll
                for (int n = 0; n < 4; n++)
                    acc[m][n] = __builtin_amdgcn_mfma_f32_16x16x32_bf16(a[m], bfr[n], acc[m][n], 0, 0, 0);
        }
    }
    // epilogue: C/D layout col=lane&15, row=(lane>>4)*4+reg
    #pragma unroll
    for (int m = 0; m < 4; m++) {
        #pragma unroll
        for (int n = 0; n < 4; n++) {
            int col = bn + wc*64 + n*16 + l15;
            float bv = bias[col];
            #pragma unroll
            for (int r = 0; r < 4; r++) {
                int row = bm + wr*64 + m*16 + g*4 + r;
                C[(size_t)row * N + col] = acc[m][n][r] + bv;
            }
        }
    }
}

// ---------------------------------------------------------------------------
// Normalized FWHT over 64 lanes via shuffle butterflies.
// ---------------------------------------------------------------------------
__device__ __forceinline__ float fwht64(float x, int lane)
{
    #pragma unroll
    for (int h = 1; h < 64; h <<= 1) {
        float y = __shfl_xor(x, h, 64);
        x = (lane & h) ? (y - x) : (x + y);
    }
    return x * 0.125f;
}

// qkv f32 -> transformed q,k (b,h,s,d) bf16 and v^T (b,h,d,s) bf16.
__global__ __launch_bounds__(256)
void transform_split(const float* __restrict__ qkv, const float* __restrict__ diag,
                     const float* __restrict__ alphap, const float* __restrict__ biasp,
                     u16* __restrict__ qh, u16* __restrict__ kh, u16* __restrict__ vt)
{
    const int lane = threadIdx.x & 63;
    const int w = (blockIdx.x * 256 + threadIdx.x) >> 6;
    const int h = w & (H_ - 1);
    const int s = (w >> 4) & (S_ - 1);
    const int b = w >> 15;
    const int bh = b * H_ + h;
    const float alpha = alphap[0];
    const float dg = diag[lane];
    const float bb = biasp[lane];
    const float* row = qkv + (size_t)(b * S_ + s) * N3_;
    const size_t o = ((size_t)bh * S_ + s) * 64 + lane;

    float xq = row[h*64 + lane];
    float t = fwht64(fwht64(xq, lane) * dg, lane);
    qh[o] = f2bf(xq + alpha * t + bb);
    float xk = row[E_ + h*64 + lane];
    t = fwht64(fwht64(xk, lane) * dg, lane);
    kh[o] = f2bf(xk + alpha * t + bb);
    vt[((size_t)bh * 64 + lane) * S_ + s] = f2bf(row[2*E_ + h*64 + lane]);
}

// ---------------------------------------------------------------------------
// MFMA flash attention: block = 64 q-rows of one (b,h); 4 waves x 16 rows.
// K/V tiles of 64 keys staged via global_load_lds; online softmax in f32;
// P relayout through wave-private padded LDS; PV via mfma.
// ---------------------------------------------------------------------------
__global__ __launch_bounds__(256)
void flash_mfma(const u16* __restrict__ qh, const u16* __restrict__ kh,
                const u16* __restrict__ vt, const int* __restrict__ mask,
                float* __restrict__ attn /* (b,s,H,D) f32 */)
{
    __shared__ u16 Ks[64*64];        // [key][d]
    __shared__ u16 Vs[64*64];        // [d][key]  (from v^T global)
    __shared__ u16 Ps[4][16*72];     // wave-private P, padded (144B rows: 2-way max)
    const int tid = threadIdx.x;
    const int lane = tid & 63;
    const int w = tid >> 6;
    const int l15 = lane & 15, g = lane >> 4;
    const int bh = blockIdx.y;
    const int b = bh >> 4, h = bh & 15;
    const int q0 = blockIdx.x * 64;
    const u16* qb = qh + (size_t)bh * S_ * 64;
    const u16* kb = kh + (size_t)bh * S_ * 64;
    const u16* vb = vt + (size_t)bh * 64 * S_;

    // Q fragments pinned in registers: A row = lane&15, k = kc*32+g*8+j
    bf16x8 qa0, qa1;
    {
        const u16* qr = qb + (size_t)(q0 + w*16 + l15) * 64 + g*8;
        qa0 = *(const bf16x8*)qr;
        qa1 = *(const bf16x8*)(qr + 32);
    }
    const f32x4 z4 = {0.f, 0.f, 0.f, 0.f};
    float m_i[4], l_i[4];
    f32x4 acc[4];
    #pragma unroll
    for (int r = 0; r < 4; r++) { m_i[r] = -INFINITY; l_i[r] = 0.f; }
    #pragma unroll
    for (int n = 0; n < 4; n++) acc[n] = z4;

    for (int t = 0; t < S_/64; t++) {
        const int k0 = t * 64;
        __syncthreads();                       // prior tile fully consumed
        #pragma unroll
        for (int u = 0; u < 2; u++) {
            int f = u * 256 + tid;             // 512 chunks of 16B per 8KB tile
            gld_lds16(kb + (size_t)(k0 + (f >> 3)) * 64 + (f & 7) * 8,
                      (char*)Ks + ((f >> 6) << 10));
            gld_lds16(vb + (size_t)(f >> 3) * S_ + k0 + (f & 7) * 8,
                      (char*)Vs + ((f >> 6) << 10));
        }
        __syncthreads();                       // staging complete (vmcnt drained)

        // S = Q @ K^T  (B col = lane&15 = key, k = d)
        f32x4 sv[4];
        #pragma unroll
        for (int nt = 0; nt < 4; nt++) sv[nt] = z4;
        #pragma unroll
        for (int nt = 0; nt < 4; nt++) {
            bf16x8 kf0 = *(const bf16x8*)&Ks[(nt*16 + l15)*64 + g*8];
            bf16x8 kf1 = *(const bf16x8*)&Ks[(nt*16 + l15)*64 + 32 + g*8];
            sv[nt] = __builtin_amdgcn_mfma_f32_16x16x32_bf16(qa0, kf0, sv[nt], 0, 0, 0);
            sv[nt] = __builtin_amdgcn_mfma_f32_16x16x32_bf16(qa1, kf1, sv[nt], 0, 0, 0);
        }
        // scale + mask (C/D: col=lane&15 -> key, row=g*4+r -> q)
        #pragma unroll
        for (int nt = 0; nt < 4; nt++) {
            int mk = mask[b * S_ + k0 + nt*16 + l15];
            #pragma unroll
            for (int r = 0; r < 4; r++)
                sv[nt][r] = mk ? sv[nt][r] * 0.125f : -INFINITY;
        }
        // online softmax per q-row (reduce across the 16 l15 lanes)
        float fsc[4], rsum[4];
        #pragma unroll
        for (int r = 0; r < 4; r++) {
            float rm = fmaxf(fmaxf(sv[0][r], sv[1][r]), fmaxf(sv[2][r], sv[3][r]));
            #pragma unroll
            for (int mm = 1; mm < 16; mm <<= 1)
                rm = fmaxf(rm, __shfl_xor(rm, mm, 64));
            float mn = fmaxf(m_i[r], rm);
            if (mn == -INFINITY) {
                fsc[r] = 1.f; rsum[r] = 0.f;
                #pragma unroll
                for (int nt = 0; nt < 4; nt++) sv[nt][r] = 0.f;
            } else {
                fsc[r] = __expf(m_i[r] - mn);
                float rs = 0.f;
                #pragma unroll
                for (int nt = 0; nt < 4; nt++) {
                    float p = __expf(sv[nt][r] - mn);
                    sv[nt][r] = p; rs += p;
                }
                rsum[r] = rs;
            }
            m_i[r] = mn;
            #pragma unroll
            for (int mm = 1; mm < 16; mm <<= 1)
                rsum[r] += __shfl_xor(rsum[r], mm, 64);
            l_i[r] = l_i[r] * fsc[r] + rsum[r];
            #pragma unroll
            for (int n = 0; n < 4; n++) acc[n][r] *= fsc[r];
        }
        // P -> wave-private LDS (A-operand layout: row=q, k=key)
        #pragma unroll
        for (int nt = 0; nt < 4; nt++)
            #pragma unroll
            for (int r = 0; r < 4; r++)
                Ps[w][(g*4 + r)*72 + nt*16 + l15] = f2bf(sv[nt][r]);
        asm volatile("s_waitcnt lgkmcnt(0)" ::: "memory");
        __builtin_amdgcn_sched_barrier(0);
        // O += P @ V
        #pragma unroll
        for (int kc = 0; kc < 2; kc++) {
            bf16x8 pa = *(const bf16x8*)&Ps[w][l15*72 + kc*32 + g*8];
            #pragma unroll
            for (int nd = 0; nd < 4; nd++) {
                bf16x8 vf = *(const bf16x8*)&Vs[(nd*16 + l15)*64 + kc*32 + g*8];
                acc[nd] = __builtin_amdgcn_mfma_f32_16x16x32_bf16(pa, vf, acc[nd], 0, 0, 0);
            }
        }
    }
    // epilogue: q = q0 + w*16 + g*4 + r, d = nd*16 + l15
    #pragma unroll
    for (int r = 0; r < 4; r++) {
        float inv = l_i[r] > 0.f ? 1.f / l_i[r] : 0.f;
        int q = q0 + w*16 + g*4 + r;
        #pragma unroll
        for (int nd = 0; nd < 4; nd++)
            attn[(size_t)(b * S_ + q) * E_ + h*64 + nd*16 + l15] = acc[nd][r] * inv;
    }
}

// ---------------------------------------------------------------------------
extern "C" void kernel_launch(void* const* d_in, const int* in_sizes, int n_in,
                              void* d_out, int out_size, void* d_ws, size_t ws_size,
                              hipStream_t stream)
{
    (void)in_sizes; (void)n_in; (void)out_size; (void)ws_size;
    const float* x     = (const float*)d_in[0];
    const int*   mask  = (const int*)  d_in[1];
    const float* Wqkv  = (const float*)d_in[2];
    const float* bqkv  = (const float*)d_in[3];
    const float* Wout  = (const float*)d_in[4];
    const float* bout  = (const float*)d_in[5];
    const float* diag  = (const float*)d_in[6];
    const float* alpha = (const float*)d_in[7];
    const float* biash = (const float*)d_in[8];
    float* out = (float*)d_out;

    // Workspace map (bytes). Peak 96.5 MB (< 100.7 MB used by passing round 1).
    char* ws = (char*)d_ws;
    float* qkv  = (float*)(ws + 0);            // 50,331,648 (f32 4096x3072)
    u16* wq_hi  = (u16*)(ws + 50331648);       //  6,291,456 (Wqkv^T hi)   } dead after gemm1
    u16* wq_lo  = (u16*)(ws + 56623104);       //  6,291,456 (Wqkv^T lo)   }
    u16* qh     = (u16*)(ws + 50331648);       //  8,388,608 (overlays wq_* after gemm1)
    u16* khp    = (u16*)(ws + 58720256);       //  8,388,608
    u16* vt     = (u16*)(ws + 67108864);       //  8,388,608
    u16* x_hi   = (u16*)(ws + 75497472);       //  8,388,608 } dead after gemm1,
    u16* x_lo   = (u16*)(ws + 83886080);       //  8,388,608 } reused for attn splits
    float* attn = (float*)(ws + 0);            // 16,777,216 (overlays dead qkv)
    u16* a_hi   = x_hi;
    u16* a_lo   = x_lo;
    u16* wo_hi  = (u16*)(ws + 92274688);       //  2,097,152
    u16* wo_lo  = (u16*)(ws + 94371840);       //  2,097,152  [end 96,468,992]

    // 1) splits
    split_a<<<4096, 256, 0, stream>>>(x, x_hi, x_lo, M_ * E_ / 4);
    split_bt<<<(E_ * N3_ + 255) / 256, 256, 0, stream>>>(Wqkv, wq_hi, wq_lo, E_, N3_);
    split_bt<<<(E_ * E_ + 255) / 256, 256, 0, stream>>>(Wout, wo_hi, wo_lo, E_, E_);
    // 2) qkv = x @ Wqkv + bqkv (3-term split bf16 MFMA)
    gemm3<<<dim3(N3_ / 128, M_ / 128), 256, 0, stream>>>(
        x_hi, x_lo, wq_hi, wq_lo, bqkv, qkv, M_, N3_, E_);
    // 3) FWHT transform, split heads, emit bf16 q,k and v^T
    transform_split<<<(B_ * S_ * H_) / 4, 256, 0, stream>>>(
        qkv, diag, alpha, biash, qh, khp, vt);
    // 4) MFMA flash attention
    flash_mfma<<<dim3(S_ / 64, B_ * H_), 256, 0, stream>>>(qh, khp, vt, mask, attn);
    // 5) out = attn @ Wout + bout (3-term split bf16 MFMA)
    split_a<<<4096, 256, 0, stream>>>(attn, a_hi, a_lo, M_ * E_ / 4);
    gemm3<<<dim3(E_ / 128, M_ / 128), 256, 0, stream>>>(
        a_hi, a_lo, wo_hi, wo_lo, bout, out, M_, E_, E_);
}

// Round 3
// 391.130 us; speedup vs baseline: 5.2017x; 1.1842x over previous
//
#include <hip/hip_runtime.h>
#include <cmath>

#define B_ 2
#define S_ 2048
#define E_ 1024
#define H_ 16
#define M_ (B_*S_)    // 4096
#define N3_ (3*E_)    // 3072

typedef unsigned short u16;
typedef unsigned int u32;
typedef __attribute__((ext_vector_type(8))) short bf16x8;   // 8 bf16 = 4 VGPRs
typedef __attribute__((ext_vector_type(4))) float f32x4;

// fp32 -> bf16 round-to-nearest-even
__device__ __forceinline__ u16 f2bf(float x) {
    unsigned u = __float_as_uint(x);
    return (u16)((u + 0x7FFFu + ((u >> 16) & 1u)) >> 16);
}
__device__ __forceinline__ float bf2f(u16 h) {
    return __uint_as_float((u32)h << 16);
}
__device__ __forceinline__ void gld_lds16(const void* g, void* l) {
    __builtin_amdgcn_global_load_lds((const __attribute__((address_space(1))) void*)g,
                                     (__attribute__((address_space(3))) void*)l, 16, 0, 0);
}

// ---------------------------------------------------------------------------
// Elementwise split: in (f32, n4*4 elems) -> hi/lo bf16 arrays (same layout).
// ---------------------------------------------------------------------------
__global__ __launch_bounds__(256)
void split_a(const float* __restrict__ in, u16* __restrict__ hi, u16* __restrict__ lo, int n4)
{
    int i = blockIdx.x * 256 + threadIdx.x;
    if (i >= n4) return;
    float4 v = ((const float4*)in)[i];
    float vv[4] = {v.x, v.y, v.z, v.w};
    unsigned hp[2], lp[2];
    u16 h[4], l[4];
    #pragma unroll
    for (int j = 0; j < 4; j++) {
        h[j] = f2bf(vv[j]);
        float hf = bf2f(h[j]);
        l[j] = f2bf(vv[j] - hf);
    }
    hp[0] = (unsigned)h[0] | ((unsigned)h[1] << 16);
    hp[1] = (unsigned)h[2] | ((unsigned)h[3] << 16);
    lp[0] = (unsigned)l[0] | ((unsigned)l[1] << 16);
    lp[1] = (unsigned)l[2] | ((unsigned)l[3] << 16);
    ((uint2*)hi)[i] = make_uint2(hp[0], hp[1]);
    ((uint2*)lo)[i] = make_uint2(lp[0], lp[1]);
}

// ---------------------------------------------------------------------------
// Transpose+split: W [K][N] f32 -> Bt_hi/lo [N][K] bf16 (B^T for GEMM B-frags).
// ---------------------------------------------------------------------------
__global__ __launch_bounds__(256)
void split_bt(const float* __restrict__ W, u16* __restrict__ hi, u16* __restrict__ lo,
              int K, int N)
{
    int idx = blockIdx.x * 256 + threadIdx.x;
    if (idx >= K * N) return;
    int k = idx / N, nn = idx - k * N;
    float v = W[idx];
    u16 h = f2bf(v);
    float hf = bf2f(h);
    u16 l = f2bf(v - hf);
    size_t o = (size_t)nn * K + k;
    hi[o] = h; lo[o] = l;
}

// ---------------------------------------------------------------------------
// Split-bf16 3-term GEMM: C[M][N] f32 = Ah@Bh + Al@Bh + Ah@Bl + bias
// (unchanged from round 2 — next-round candidate for 256^2 8-phase port)
// ---------------------------------------------------------------------------
__global__ __launch_bounds__(256)
void gemm3(const u16* __restrict__ Ahi, const u16* __restrict__ Alo,
           const u16* __restrict__ Bhi, const u16* __restrict__ Blo,
           const float* __restrict__ bias, float* __restrict__ C,
           int M, int N, int K)
{
    __shared__ u16 As[128*64];   // [m][k] linear
    __shared__ u16 Bs[128*64];   // [n][k] linear
    const int tid = threadIdx.x;
    const int lane = tid & 63;
    const int w = tid >> 6;
    const int wr = w >> 1, wc = w & 1;
    const int l15 = lane & 15, g = lane >> 4;
    const int bm = blockIdx.y * 128;
    const int bn = blockIdx.x * 128;
    const f32x4 z4 = {0.f, 0.f, 0.f, 0.f};
    f32x4 acc[4][4];
    #pragma unroll
    for (int m = 0; m < 4; m++)
        #pragma unroll
        for (int n = 0; n < 4; n++) acc[m][n] = z4;

    const int niter = 3 * K / 64;
    for (int i = 0; i < niter; i++) {
        int kb = i * 64;
        const u16* Ab; const u16* Bb; int ko;
        if (kb < K)          { Ab = Ahi; Bb = Bhi; ko = kb; }
        else if (kb < 2 * K) { Ab = Alo; Bb = Bhi; ko = kb - K; }
        else                 { Ab = Ahi; Bb = Blo; ko = kb - 2 * K; }
        __syncthreads();
        #pragma unroll
        for (int u = 0; u < 4; u++) {
            int f = u * 256 + tid;                       // 1024 chunks of 16B per tile
            gld_lds16(Ab + (size_t)(bm + (f >> 3)) * K + ko + (f & 7) * 8,
                      (char*)As + ((f >> 6) << 10));
            gld_lds16(Bb + (size_t)(bn + (f >> 3)) * K + ko + (f & 7) * 8,
                      (char*)Bs + ((f >> 6) << 10));
        }
        __syncthreads();
        #pragma unroll
        for (int kc = 0; kc < 2; kc++) {
            bf16x8 a[4], bfr[4];
            #pragma unroll
            for (int m = 0; m < 4; m++)
                a[m] = *(const bf16x8*)&As[(wr*64 + m*16 + l15)*64 + kc*32 + g*8];
            #pragma unroll
            for (int n = 0; n < 4; n++)
                bfr[n] = *(const bf16x8*)&Bs[(wc*64 + n*16 + l15)*64 + kc*32 + g*8];
            #pragma unroll
            for (int m = 0; m < 4; m++)
                #pragma unroll
                for (int n = 0; n < 4; n++)
                    acc[m][n] = __builtin_amdgcn_mfma_f32_16x16x32_bf16(a[m], bfr[n], acc[m][n], 0, 0, 0);
        }
    }
    // epilogue: C/D layout col=lane&15, row=(lane>>4)*4+reg
    #pragma unroll
    for (int m = 0; m < 4; m++) {
        #pragma unroll
        for (int n = 0; n < 4; n++) {
            int col = bn + wc*64 + n*16 + l15;
            float bv = bias[col];
            #pragma unroll
            for (int r = 0; r < 4; r++) {
                int row = bm + wr*64 + m*16 + g*4 + r;
                C[(size_t)row * N + col] = acc[m][n][r] + bv;
            }
        }
    }
}

// ---------------------------------------------------------------------------
// Normalized FWHT over 64 lanes via shuffle butterflies.
// ---------------------------------------------------------------------------
__device__ __forceinline__ float fwht64(float x, int lane)
{
    #pragma unroll
    for (int h = 1; h < 64; h <<= 1) {
        float y = __shfl_xor(x, h, 64);
        x = (lane & h) ? (y - x) : (x + y);
    }
    return x * 0.125f;
}

// qkv f32 -> transformed q,k (b,h,s,d) bf16 and v^T (b,h,d,s) bf16.
__global__ __launch_bounds__(256)
void transform_split(const float* __restrict__ qkv, const float* __restrict__ diag,
                     const float* __restrict__ alphap, const float* __restrict__ biasp,
                     u16* __restrict__ qh, u16* __restrict__ kh, u16* __restrict__ vt)
{
    const int lane = threadIdx.x & 63;
    const int w = (blockIdx.x * 256 + threadIdx.x) >> 6;
    const int h = w & (H_ - 1);
    const int s = (w >> 4) & (S_ - 1);
    const int b = w >> 15;
    const int bh = b * H_ + h;
    const float alpha = alphap[0];
    const float dg = diag[lane];
    const float bb = biasp[lane];
    const float* row = qkv + (size_t)(b * S_ + s) * N3_;
    const size_t o = ((size_t)bh * S_ + s) * 64 + lane;

    float xq = row[h*64 + lane];
    float t = fwht64(fwht64(xq, lane) * dg, lane);
    qh[o] = f2bf(xq + alpha * t + bb);
    float xk = row[E_ + h*64 + lane];
    t = fwht64(fwht64(xk, lane) * dg, lane);
    kh[o] = f2bf(xk + alpha * t + bb);
    vt[((size_t)bh * 64 + lane) * S_ + s] = f2bf(row[2*E_ + h*64 + lane]);
}

// ---------------------------------------------------------------------------
// MFMA flash attention v2:
//  - swapped QK^T (S^T = mfma(K,Q)) -> per-lane-scalar online softmax (q=l15)
//  - XOR-swizzled K/V LDS tiles (pre-swizzled global src + swizzled reads)
//  - mask as additive-bias vector staged once in LDS
//  - P packed via ds_write_b64; PV as O^T = mfma(V^T, P^T)
//  - epilogue emits hi/lo bf16 split directly for the out-GEMM
// ---------------------------------------------------------------------------
__global__ __launch_bounds__(256)
void flash_mfma(const u16* __restrict__ qh, const u16* __restrict__ kh,
                const u16* __restrict__ vt, const int* __restrict__ mask,
                u16* __restrict__ ohi, u16* __restrict__ olo)
{
    __shared__ u16 Ks[64*64];        // [key][d], XOR-swizzled
    __shared__ u16 Vs[64*64];        // [d][key], XOR-swizzled
    __shared__ u16 Ps[4][16*72];     // wave-private P [q=l15][key], pad 72
    __shared__ float smask[S_];      // additive mask bias (0 or -3e38)
    const int tid = threadIdx.x;
    const int lane = tid & 63;
    const int w = tid >> 6;
    const int l15 = lane & 15, g = lane >> 4;
    const int bh = blockIdx.y;
    const int b = bh >> 4, h = bh & 15;
    const int q0 = blockIdx.x * 64;
    const u16* qb = qh + (size_t)bh * S_ * 64;
    const u16* kb = kh + (size_t)bh * S_ * 64;
    const u16* vb = vt + (size_t)bh * 64 * S_;

    // stage mask bias once (coalesced; first __syncthreads below guards it)
    #pragma unroll
    for (int i = 0; i < S_/256; i++)
        smask[i*256 + tid] = mask[b*S_ + i*256 + tid] ? 0.f : -3.0e38f;

    // Q fragments pinned in registers (B-operand: col=q=l15, k=d=kc*32+g*8+j)
    bf16x8 qf0, qf1;
    {
        const u16* qr = qb + (size_t)(q0 + w*16 + l15) * 64 + g*8;
        qf0 = *(const bf16x8*)qr;
        qf1 = *(const bf16x8*)(qr + 32);
    }
    const f32x4 z4 = {0.f, 0.f, 0.f, 0.f};
    float m_i = -1.0e30f, l_i = 0.f;
    f32x4 acc[4];    // O^T: acc[nd][r] = O[q=l15][d = nd*16 + g*4 + r]
    #pragma unroll
    for (int n = 0; n < 4; n++) acc[n] = z4;

    const int swz = (l15 & 7) << 3;   // u16-index XOR for swizzled reads

    for (int t = 0; t < S_/64; t++) {
        const int k0 = t * 64;
        __syncthreads();                       // prior tile consumed (+ smask ready)
        #pragma unroll
        for (int u = 0; u < 2; u++) {
            int f = u * 256 + tid;             // 512 chunks of 16B per 8KB tile
            int r = f >> 3;
            int cs = ((f & 7) ^ (r & 7)) * 8;  // pre-swizzled source column
            gld_lds16(kb + (size_t)(k0 + r) * 64 + cs, (char*)Ks + ((f >> 6) << 10));
            gld_lds16(vb + (size_t)r * S_ + k0 + cs,   (char*)Vs + ((f >> 6) << 10));
        }
        __syncthreads();                       // staging complete

        // S^T = K @ Q : rows=key (A-side), cols=q (B-side)
        f32x4 sv[4];
        #pragma unroll
        for (int nt = 0; nt < 4; nt++) {
            int row = nt*16 + l15;             // key row; row&7 == l15&7
            bf16x8 ka0 = *(const bf16x8*)&Ks[(row*64 +  0 + g*8) ^ swz];
            bf16x8 ka1 = *(const bf16x8*)&Ks[(row*64 + 32 + g*8) ^ swz];
            sv[nt] = __builtin_amdgcn_mfma_f32_16x16x32_bf16(ka0, qf0, z4, 0, 0, 0);
            sv[nt] = __builtin_amdgcn_mfma_f32_16x16x32_bf16(ka1, qf1, sv[nt], 0, 0, 0);
        }
        // scale + additive mask bias (key = k0 + nt*16 + g*4 + r)
        #pragma unroll
        for (int nt = 0; nt < 4; nt++) {
            float4 mb = *(const float4*)&smask[k0 + nt*16 + g*4];
            sv[nt][0] = fmaf(sv[nt][0], 0.125f, mb.x);
            sv[nt][1] = fmaf(sv[nt][1], 0.125f, mb.y);
            sv[nt][2] = fmaf(sv[nt][2], 0.125f, mb.z);
            sv[nt][3] = fmaf(sv[nt][3], 0.125f, mb.w);
        }
        // online softmax — all state per-lane scalar (q = l15)
        float rm = fmaxf(fmaxf(sv[0][0], sv[0][1]), fmaxf(sv[0][2], sv[0][3]));
        #pragma unroll
        for (int nt = 1; nt < 4; nt++) {
            rm = fmaxf(rm, fmaxf(sv[nt][0], sv[nt][1]));
            rm = fmaxf(rm, fmaxf(sv[nt][2], sv[nt][3]));
        }
        rm = fmaxf(rm, __shfl_xor(rm, 16, 64));
        rm = fmaxf(rm, __shfl_xor(rm, 32, 64));
        const int grow = __any(rm > m_i);      // wave-uniform defer check
        float mn = m_i, fsc = 1.f;
        if (grow) {
            mn = fmaxf(m_i, rm);
            fsc = __expf(m_i - mn);
            m_i = mn;
        }
        float rs = 0.f;
        #pragma unroll
        for (int nt = 0; nt < 4; nt++)
            #pragma unroll
            for (int r = 0; r < 4; r++) {
                float p = __expf(sv[nt][r] - mn);
                sv[nt][r] = p;
                rs += p;
            }
        rs += __shfl_xor(rs, 16, 64);
        rs += __shfl_xor(rs, 32, 64);
        if (grow) {
            l_i = l_i * fsc + rs;
            #pragma unroll
            for (int n = 0; n < 4; n++)
                #pragma unroll
                for (int r = 0; r < 4; r++) acc[n][r] *= fsc;
        } else {
            l_i += rs;
        }
        // pack P -> wave-private LDS ([q=l15][key], keys nt*16+g*4+{0..3})
        #pragma unroll
        for (int nt = 0; nt < 4; nt++) {
            u32 p01 = (u32)f2bf(sv[nt][0]) | ((u32)f2bf(sv[nt][1]) << 16);
            u32 p23 = (u32)f2bf(sv[nt][2]) | ((u32)f2bf(sv[nt][3]) << 16);
            *(uint2*)&Ps[w][l15*72 + nt*16 + g*4] = make_uint2(p01, p23);
        }
        asm volatile("s_waitcnt lgkmcnt(0)" ::: "memory");
        __builtin_amdgcn_sched_barrier(0);
        // O^T += V^T @ P^T : rows=d (A-side), cols=q (B-side), k=key
        #pragma unroll
        for (int kc = 0; kc < 2; kc++) {
            bf16x8 pb = *(const bf16x8*)&Ps[w][l15*72 + kc*32 + g*8];
            #pragma unroll
            for (int nd = 0; nd < 4; nd++) {
                int row = nd*16 + l15;         // d row; row&7 == l15&7
                bf16x8 vf = *(const bf16x8*)&Vs[(row*64 + kc*32 + g*8) ^ swz];
                acc[nd] = __builtin_amdgcn_mfma_f32_16x16x32_bf16(vf, pb, acc[nd], 0, 0, 0);
            }
        }
    }
    // epilogue: q = q0+w*16+l15 (per-lane uniform), d = nd*16+g*4+r;
    // emit hi/lo bf16 split directly (A-operand of the out-GEMM).
    float inv = l_i > 0.f ? 1.f / l_i : 0.f;
    const int q = q0 + w*16 + l15;
    const size_t rowoff = (size_t)(b * S_ + q) * E_ + h*64;
    #pragma unroll
    for (int nd = 0; nd < 4; nd++) {
        #pragma unroll
        for (int r = 0; r < 4; r += 2) {
            float o0 = acc[nd][r]     * inv;
            float o1 = acc[nd][r + 1] * inv;
            u16 h0 = f2bf(o0), h1 = f2bf(o1);
            u16 lo0 = f2bf(o0 - bf2f(h0)), lo1 = f2bf(o1 - bf2f(h1));
            int col = nd*16 + g*4 + r;
            *(u32*)&ohi[rowoff + col] = (u32)h0 | ((u32)h1 << 16);
            *(u32*)&olo[rowoff + col] = (u32)lo0 | ((u32)lo1 << 16);
        }
    }
}

// ---------------------------------------------------------------------------
extern "C" void kernel_launch(void* const* d_in, const int* in_sizes, int n_in,
                              void* d_out, int out_size, void* d_ws, size_t ws_size,
                              hipStream_t stream)
{
    (void)in_sizes; (void)n_in; (void)out_size; (void)ws_size;
    const float* x     = (const float*)d_in[0];
    const int*   mask  = (const int*)  d_in[1];
    const float* Wqkv  = (const float*)d_in[2];
    const float* bqkv  = (const float*)d_in[3];
    const float* Wout  = (const float*)d_in[4];
    const float* bout  = (const float*)d_in[5];
    const float* diag  = (const float*)d_in[6];
    const float* alpha = (const float*)d_in[7];
    const float* biash = (const float*)d_in[8];
    float* out = (float*)d_out;

    // Workspace map (bytes). Peak 96.5 MB.
    char* ws = (char*)d_ws;
    float* qkv  = (float*)(ws + 0);            // 50,331,648 (f32 4096x3072)
    u16* wq_hi  = (u16*)(ws + 50331648);       //  6,291,456 (Wqkv^T hi)   } dead after gemm1
    u16* wq_lo  = (u16*)(ws + 56623104);       //  6,291,456 (Wqkv^T lo)   }
    u16* qh     = (u16*)(ws + 50331648);       //  8,388,608 (overlays wq_* after gemm1)
    u16* khp    = (u16*)(ws + 58720256);       //  8,388,608
    u16* vt     = (u16*)(ws + 67108864);       //  8,388,608
    u16* x_hi   = (u16*)(ws + 75497472);       //  8,388,608 } x split for gemm1;
    u16* x_lo   = (u16*)(ws + 83886080);       //  8,388,608 } reused as attn hi/lo after
    u16* a_hi   = x_hi;
    u16* a_lo   = x_lo;
    u16* wo_hi  = (u16*)(ws + 92274688);       //  2,097,152
    u16* wo_lo  = (u16*)(ws + 94371840);       //  2,097,152  [end 96,468,992]

    // 1) splits
    split_a<<<4096, 256, 0, stream>>>(x, x_hi, x_lo, M_ * E_ / 4);
    split_bt<<<(E_ * N3_ + 255) / 256, 256, 0, stream>>>(Wqkv, wq_hi, wq_lo, E_, N3_);
    split_bt<<<(E_ * E_ + 255) / 256, 256, 0, stream>>>(Wout, wo_hi, wo_lo, E_, E_);
    // 2) qkv = x @ Wqkv + bqkv (3-term split bf16 MFMA)
    gemm3<<<dim3(N3_ / 128, M_ / 128), 256, 0, stream>>>(
        x_hi, x_lo, wq_hi, wq_lo, bqkv, qkv, M_, N3_, E_);
    // 3) FWHT transform, split heads, emit bf16 q,k and v^T
    transform_split<<<(B_ * S_ * H_) / 4, 256, 0, stream>>>(
        qkv, diag, alpha, biash, qh, khp, vt);
    // 4) MFMA flash attention (writes hi/lo split directly)
    flash_mfma<<<dim3(S_ / 64, B_ * H_), 256, 0, stream>>>(
        qh, khp, vt, mask, a_hi, a_lo);
    // 5) out = attn @ Wout + bout (3-term split bf16 MFMA)
    gemm3<<<dim3(E_ / 128, M_ / 128), 256, 0, stream>>>(
        a_hi, a_lo, wo_hi, wo_lo, bout, out, M_, E_, E_);
}

// Round 4
// 322.384 us; speedup vs baseline: 6.3109x; 1.2132x over previous
//
#include <hip/hip_runtime.h>
#include <cmath>

#define B_ 2
#define S_ 2048
#define E_ 1024
#define H_ 16
#define M_ (B_*S_)    // 4096
#define N3_ (3*E_)    // 3072

typedef unsigned short u16;
typedef unsigned int u32;
typedef __attribute__((ext_vector_type(8))) short bf16x8;     // 8x16b = 4 VGPRs
typedef __attribute__((ext_vector_type(8))) _Float16 f16x8;
typedef __attribute__((ext_vector_type(4))) float f32x4;

// fp32 -> bf16 round-to-nearest-even
__device__ __forceinline__ u16 f2bf(float x) {
    unsigned u = __float_as_uint(x);
    return (u16)((u + 0x7FFFu + ((u >> 16) & 1u)) >> 16);
}
__device__ __forceinline__ float bf2f(u16 h) {
    return __uint_as_float((u32)h << 16);
}
__device__ __forceinline__ u16 f2h(float x) {
    _Float16 h = (_Float16)x;
    return __builtin_bit_cast(u16, h);
}
__device__ __forceinline__ float h2f(u16 b) {
    return (float)__builtin_bit_cast(_Float16, b);
}
__device__ __forceinline__ void gld_lds16(const void* g, void* l) {
    __builtin_amdgcn_global_load_lds((const __attribute__((address_space(1))) void*)g,
                                     (__attribute__((address_space(3))) void*)l, 16, 0, 0);
}

template<bool F16>
__device__ __forceinline__ f32x4 mma16(bf16x8 a, bf16x8 b, f32x4 c) {
    if constexpr (F16)
        return __builtin_amdgcn_mfma_f32_16x16x32_f16(
            __builtin_bit_cast(f16x8, a), __builtin_bit_cast(f16x8, b), c, 0, 0, 0);
    else
        return __builtin_amdgcn_mfma_f32_16x16x32_bf16(a, b, c, 0, 0, 0);
}

// ---------------------------------------------------------------------------
// x (f32) -> fp16 hi/lo split (same layout)
// ---------------------------------------------------------------------------
__global__ __launch_bounds__(256)
void split_a_f16(const float* __restrict__ in, u16* __restrict__ hi, u16* __restrict__ lo, int n4)
{
    int i = blockIdx.x * 256 + threadIdx.x;
    if (i >= n4) return;
    float4 v = ((const float4*)in)[i];
    float vv[4] = {v.x, v.y, v.z, v.w};
    u16 h[4], l[4];
    #pragma unroll
    for (int j = 0; j < 4; j++) {
        h[j] = f2h(vv[j]);
        l[j] = f2h(vv[j] - h2f(h[j]));
    }
    ((uint2*)hi)[i] = make_uint2((u32)h[0] | ((u32)h[1] << 16), (u32)h[2] | ((u32)h[3] << 16));
    ((uint2*)lo)[i] = make_uint2((u32)l[0] | ((u32)l[1] << 16), (u32)l[2] | ((u32)l[3] << 16));
}

// W [K][N] f32 -> B^T [N][K] fp16 (hi only — 2-term scheme needs no B-lo)
__global__ __launch_bounds__(256)
void split_bt_f16hi(const float* __restrict__ W, u16* __restrict__ hi, int K, int N)
{
    int idx = blockIdx.x * 256 + threadIdx.x;
    if (idx >= K * N) return;
    int k = idx / N, nn = idx - k * N;
    hi[(size_t)nn * K + k] = f2h(W[idx]);
}

// W [K][N] f32 -> B^T [N][K] bf16 hi/lo (for the out-projection, 3-term)
__global__ __launch_bounds__(256)
void split_bt(const float* __restrict__ W, u16* __restrict__ hi, u16* __restrict__ lo,
              int K, int N)
{
    int idx = blockIdx.x * 256 + threadIdx.x;
    if (idx >= K * N) return;
    int k = idx / N, nn = idx - k * N;
    float v = W[idx];
    u16 h = f2bf(v);
    u16 l = f2bf(v - bf2f(h));
    size_t o = (size_t)nn * K + k;
    hi[o] = h; lo[o] = l;
}

// ---------------------------------------------------------------------------
// Multi-term split GEMM, single-stage-per-K-block:
//   NT=2 (fp16):  C = Ah@Bh + Al@Bh + bias          (tiles Ah,Al,Bh; 48KB LDS)
//   NT=3 (bf16):  C = Ah@Bh + Al@Bh + Ah@Bl + bias  (tiles Ah,Al,Bh,Bl; 64KB)
// 128x128 tile, BK=64, 4 waves (2x2), XOR-swizzled LDS (pre-swizzled global
// source per rule #21), 2 barriers per K-block.
// A*: [M][K] row-major. B*: B^T = [N][K] row-major.
// ---------------------------------------------------------------------------
template<int NT, bool F16>
__global__ __launch_bounds__(256)
void gemm_t(const u16* __restrict__ Ahi, const u16* __restrict__ Alo,
            const u16* __restrict__ Bhi, const u16* __restrict__ Blo,
            const float* __restrict__ bias, float* __restrict__ C,
            int M, int N, int K)
{
    __shared__ u16 smem[(NT + 1) * 8192];   // (NT+1) tiles of 128x64 u16
    const int tid = threadIdx.x;
    const int lane = tid & 63;
    const int w = tid >> 6;
    const int wr = w >> 1, wc = w & 1;
    const int l15 = lane & 15, g = lane >> 4;
    const int bm = blockIdx.y * 128;
    const int bn = blockIdx.x * 128;
    const int swz = (l15 & 7) << 3;          // u16-index XOR for swizzled reads
    const f32x4 z4 = {0.f, 0.f, 0.f, 0.f};
    f32x4 acc[4][4];
    #pragma unroll
    for (int m = 0; m < 4; m++)
        #pragma unroll
        for (int n = 0; n < 4; n++) acc[m][n] = z4;

    for (int ko = 0; ko < K; ko += 64) {
        __syncthreads();                     // prior K-block fully consumed
        #pragma unroll
        for (int u = 0; u < 4 * (NT + 1); u++) {
            int f = u * 256 + tid;           // 16B chunk id; tile = u>>2 (const)
            int tile = u >> 2;
            int r = (f >> 3) & 127;          // row within tile
            int cs = ((f & 7) ^ (r & 7)) << 3;   // pre-swizzled source column
            const u16* src;
            if (tile == 0)      src = Ahi + (size_t)(bm + r) * K + ko + cs;
            else if (tile == 1) src = Alo + (size_t)(bm + r) * K + ko + cs;
            else if (tile == 2) src = Bhi + (size_t)(bn + r) * K + ko + cs;
            else                src = Blo + (size_t)(bn + r) * K + ko + cs;
            gld_lds16(src, (char*)smem + ((f >> 6) << 10));
        }
        __syncthreads();                     // staging complete
        #pragma unroll
        for (int p = 0; p < NT; p++) {       // passes: (Ah,Bh),(Al,Bh)[,(Ah,Bl)]
            const u16* At = smem + ((p == 1) ? 8192 : 0);
            const u16* Bt = smem + ((NT == 3 && p == 2) ? 3 * 8192 : 2 * 8192);
            #pragma unroll
            for (int kc = 0; kc < 2; kc++) {
                bf16x8 a[4], b[4];
                #pragma unroll
                for (int m = 0; m < 4; m++)
                    a[m] = *(const bf16x8*)&At[((wr*64 + m*16 + l15)*64 + kc*32 + g*8) ^ swz];
                #pragma unroll
                for (int n = 0; n < 4; n++)
                    b[n] = *(const bf16x8*)&Bt[((wc*64 + n*16 + l15)*64 + kc*32 + g*8) ^ swz];
                #pragma unroll
                for (int m = 0; m < 4; m++)
                    #pragma unroll
                    for (int n = 0; n < 4; n++)
                        acc[m][n] = mma16<F16>(a[m], b[n], acc[m][n]);
            }
        }
    }
    // epilogue: C/D layout col=lane&15, row=(lane>>4)*4+reg
    #pragma unroll
    for (int m = 0; m < 4; m++) {
        #pragma unroll
        for (int n = 0; n < 4; n++) {
            int col = bn + wc*64 + n*16 + l15;
            float bv = bias[col];
            #pragma unroll
            for (int r = 0; r < 4; r++) {
                int row = bm + wr*64 + m*16 + g*4 + r;
                C[(size_t)row * N + col] = acc[m][n][r] + bv;
            }
        }
    }
}

// ---------------------------------------------------------------------------
// Normalized FWHT over 64 lanes via shuffle butterflies.
// ---------------------------------------------------------------------------
__device__ __forceinline__ float fwht64(float x, int lane)
{
    #pragma unroll
    for (int h = 1; h < 64; h <<= 1) {
        float y = __shfl_xor(x, h, 64);
        x = (lane & h) ? (y - x) : (x + y);
    }
    return x * 0.125f;
}

// qkv f32 -> transformed q,k (b,h,s,d) bf16 and v^T (b,h,d,s) bf16.
__global__ __launch_bounds__(256)
void transform_split(const float* __restrict__ qkv, const float* __restrict__ diag,
                     const float* __restrict__ alphap, const float* __restrict__ biasp,
                     u16* __restrict__ qh, u16* __restrict__ kh, u16* __restrict__ vt)
{
    const int lane = threadIdx.x & 63;
    const int w = (blockIdx.x * 256 + threadIdx.x) >> 6;
    const int h = w & (H_ - 1);
    const int s = (w >> 4) & (S_ - 1);
    const int b = w >> 15;
    const int bh = b * H_ + h;
    const float alpha = alphap[0];
    const float dg = diag[lane];
    const float bb = biasp[lane];
    const float* row = qkv + (size_t)(b * S_ + s) * N3_;
    const size_t o = ((size_t)bh * S_ + s) * 64 + lane;

    float xq = row[h*64 + lane];
    float t = fwht64(fwht64(xq, lane) * dg, lane);
    qh[o] = f2bf(xq + alpha * t + bb);
    float xk = row[E_ + h*64 + lane];
    t = fwht64(fwht64(xk, lane) * dg, lane);
    kh[o] = f2bf(xk + alpha * t + bb);
    vt[((size_t)bh * 64 + lane) * S_ + s] = f2bf(row[2*E_ + h*64 + lane]);
}

// ---------------------------------------------------------------------------
// MFMA flash attention (unchanged from round 3):
//  - swapped QK^T (S^T = mfma(K,Q)) -> per-lane-scalar online softmax (q=l15)
//  - XOR-swizzled K/V LDS tiles; mask as additive bias in LDS
//  - PV as O^T = mfma(V^T, P^T); epilogue emits bf16 hi/lo split
// ---------------------------------------------------------------------------
__global__ __launch_bounds__(256)
void flash_mfma(const u16* __restrict__ qh, const u16* __restrict__ kh,
                const u16* __restrict__ vt, const int* __restrict__ mask,
                u16* __restrict__ ohi, u16* __restrict__ olo)
{
    __shared__ u16 Ks[64*64];        // [key][d], XOR-swizzled
    __shared__ u16 Vs[64*64];        // [d][key], XOR-swizzled
    __shared__ u16 Ps[4][16*72];     // wave-private P [q=l15][key], pad 72
    __shared__ float smask[S_];      // additive mask bias (0 or -3e38)
    const int tid = threadIdx.x;
    const int lane = tid & 63;
    const int w = tid >> 6;
    const int l15 = lane & 15, g = lane >> 4;
    const int bh = blockIdx.y;
    const int b = bh >> 4, h = bh & 15;
    const int q0 = blockIdx.x * 64;
    const u16* qb = qh + (size_t)bh * S_ * 64;
    const u16* kb = kh + (size_t)bh * S_ * 64;
    const u16* vb = vt + (size_t)bh * 64 * S_;

    #pragma unroll
    for (int i = 0; i < S_/256; i++)
        smask[i*256 + tid] = mask[b*S_ + i*256 + tid] ? 0.f : -3.0e38f;

    bf16x8 qf0, qf1;
    {
        const u16* qr = qb + (size_t)(q0 + w*16 + l15) * 64 + g*8;
        qf0 = *(const bf16x8*)qr;
        qf1 = *(const bf16x8*)(qr + 32);
    }
    const f32x4 z4 = {0.f, 0.f, 0.f, 0.f};
    float m_i = -1.0e30f, l_i = 0.f;
    f32x4 acc[4];
    #pragma unroll
    for (int n = 0; n < 4; n++) acc[n] = z4;

    const int swz = (l15 & 7) << 3;

    for (int t = 0; t < S_/64; t++) {
        const int k0 = t * 64;
        __syncthreads();
        #pragma unroll
        for (int u = 0; u < 2; u++) {
            int f = u * 256 + tid;
            int r = f >> 3;
            int cs = ((f & 7) ^ (r & 7)) * 8;
            gld_lds16(kb + (size_t)(k0 + r) * 64 + cs, (char*)Ks + ((f >> 6) << 10));
            gld_lds16(vb + (size_t)r * S_ + k0 + cs,   (char*)Vs + ((f >> 6) << 10));
        }
        __syncthreads();

        f32x4 sv[4];
        #pragma unroll
        for (int nt = 0; nt < 4; nt++) {
            int row = nt*16 + l15;
            bf16x8 ka0 = *(const bf16x8*)&Ks[(row*64 +  0 + g*8) ^ swz];
            bf16x8 ka1 = *(const bf16x8*)&Ks[(row*64 + 32 + g*8) ^ swz];
            sv[nt] = __builtin_amdgcn_mfma_f32_16x16x32_bf16(ka0, qf0, z4, 0, 0, 0);
            sv[nt] = __builtin_amdgcn_mfma_f32_16x16x32_bf16(ka1, qf1, sv[nt], 0, 0, 0);
        }
        #pragma unroll
        for (int nt = 0; nt < 4; nt++) {
            float4 mb = *(const float4*)&smask[k0 + nt*16 + g*4];
            sv[nt][0] = fmaf(sv[nt][0], 0.125f, mb.x);
            sv[nt][1] = fmaf(sv[nt][1], 0.125f, mb.y);
            sv[nt][2] = fmaf(sv[nt][2], 0.125f, mb.z);
            sv[nt][3] = fmaf(sv[nt][3], 0.125f, mb.w);
        }
        float rm = fmaxf(fmaxf(sv[0][0], sv[0][1]), fmaxf(sv[0][2], sv[0][3]));
        #pragma unroll
        for (int nt = 1; nt < 4; nt++) {
            rm = fmaxf(rm, fmaxf(sv[nt][0], sv[nt][1]));
            rm = fmaxf(rm, fmaxf(sv[nt][2], sv[nt][3]));
        }
        rm = fmaxf(rm, __shfl_xor(rm, 16, 64));
        rm = fmaxf(rm, __shfl_xor(rm, 32, 64));
        const int grow = __any(rm > m_i);
        float mn = m_i, fsc = 1.f;
        if (grow) {
            mn = fmaxf(m_i, rm);
            fsc = __expf(m_i - mn);
            m_i = mn;
        }
        float rs = 0.f;
        #pragma unroll
        for (int nt = 0; nt < 4; nt++)
            #pragma unroll
            for (int r = 0; r < 4; r++) {
                float p = __expf(sv[nt][r] - mn);
                sv[nt][r] = p;
                rs += p;
            }
        rs += __shfl_xor(rs, 16, 64);
        rs += __shfl_xor(rs, 32, 64);
        if (grow) {
            l_i = l_i * fsc + rs;
            #pragma unroll
            for (int n = 0; n < 4; n++)
                #pragma unroll
                for (int r = 0; r < 4; r++) acc[n][r] *= fsc;
        } else {
            l_i += rs;
        }
        #pragma unroll
        for (int nt = 0; nt < 4; nt++) {
            u32 p01 = (u32)f2bf(sv[nt][0]) | ((u32)f2bf(sv[nt][1]) << 16);
            u32 p23 = (u32)f2bf(sv[nt][2]) | ((u32)f2bf(sv[nt][3]) << 16);
            *(uint2*)&Ps[w][l15*72 + nt*16 + g*4] = make_uint2(p01, p23);
        }
        asm volatile("s_waitcnt lgkmcnt(0)" ::: "memory");
        __builtin_amdgcn_sched_barrier(0);
        #pragma unroll
        for (int kc = 0; kc < 2; kc++) {
            bf16x8 pb = *(const bf16x8*)&Ps[w][l15*72 + kc*32 + g*8];
            #pragma unroll
            for (int nd = 0; nd < 4; nd++) {
                int row = nd*16 + l15;
                bf16x8 vf = *(const bf16x8*)&Vs[(row*64 + kc*32 + g*8) ^ swz];
                acc[nd] = __builtin_amdgcn_mfma_f32_16x16x32_bf16(vf, pb, acc[nd], 0, 0, 0);
            }
        }
    }
    float inv = l_i > 0.f ? 1.f / l_i : 0.f;
    const int q = q0 + w*16 + l15;
    const size_t rowoff = (size_t)(b * S_ + q) * E_ + h*64;
    #pragma unroll
    for (int nd = 0; nd < 4; nd++) {
        #pragma unroll
        for (int r = 0; r < 4; r += 2) {
            float o0 = acc[nd][r]     * inv;
            float o1 = acc[nd][r + 1] * inv;
            u16 h0 = f2bf(o0), h1 = f2bf(o1);
            u16 lo0 = f2bf(o0 - bf2f(h0)), lo1 = f2bf(o1 - bf2f(h1));
            int col = nd*16 + g*4 + r;
            *(u32*)&ohi[rowoff + col] = (u32)h0 | ((u32)h1 << 16);
            *(u32*)&olo[rowoff + col] = (u32)lo0 | ((u32)lo1 << 16);
        }
    }
}

// ---------------------------------------------------------------------------
extern "C" void kernel_launch(void* const* d_in, const int* in_sizes, int n_in,
                              void* d_out, int out_size, void* d_ws, size_t ws_size,
                              hipStream_t stream)
{
    (void)in_sizes; (void)n_in; (void)out_size; (void)ws_size;
    const float* x     = (const float*)d_in[0];
    const int*   mask  = (const int*)  d_in[1];
    const float* Wqkv  = (const float*)d_in[2];
    const float* bqkv  = (const float*)d_in[3];
    const float* Wout  = (const float*)d_in[4];
    const float* bout  = (const float*)d_in[5];
    const float* diag  = (const float*)d_in[6];
    const float* alpha = (const float*)d_in[7];
    const float* biash = (const float*)d_in[8];
    float* out = (float*)d_out;

    // Workspace map (bytes). Peak 96.5 MB.
    char* ws = (char*)d_ws;
    float* qkv  = (float*)(ws + 0);            // 50,331,648 (f32 4096x3072)
    u16* wq_hi  = (u16*)(ws + 50331648);       //  6,291,456 (Wqkv^T fp16) } dead after gemm1
    u16* qh     = (u16*)(ws + 50331648);       //  8,388,608 (overlays wq_hi after gemm1)
    u16* khp    = (u16*)(ws + 58720256);       //  8,388,608
    u16* vt     = (u16*)(ws + 67108864);       //  8,388,608
    u16* x_hi   = (u16*)(ws + 75497472);       //  8,388,608 } x fp16 split for gemm1;
    u16* x_lo   = (u16*)(ws + 83886080);       //  8,388,608 } reused as attn bf16 hi/lo
    u16* a_hi   = x_hi;
    u16* a_lo   = x_lo;
    u16* wo_hi  = (u16*)(ws + 92274688);       //  2,097,152 (Wout^T bf16 hi)
    u16* wo_lo  = (u16*)(ws + 94371840);       //  2,097,152  [end 96,468,992]

    // 1) splits
    split_a_f16<<<4096, 256, 0, stream>>>(x, x_hi, x_lo, M_ * E_ / 4);
    split_bt_f16hi<<<(E_ * N3_ + 255) / 256, 256, 0, stream>>>(Wqkv, wq_hi, E_, N3_);
    split_bt<<<(E_ * E_ + 255) / 256, 256, 0, stream>>>(Wout, wo_hi, wo_lo, E_, E_);
    // 2) qkv = x @ Wqkv + bqkv  (2-term fp16 MFMA, shared-B staging)
    gemm_t<2, true><<<dim3(N3_ / 128, M_ / 128), 256, 0, stream>>>(
        x_hi, x_lo, wq_hi, wq_hi, bqkv, qkv, M_, N3_, E_);
    // 3) FWHT transform, split heads, emit bf16 q,k and v^T
    transform_split<<<(B_ * S_ * H_) / 4, 256, 0, stream>>>(
        qkv, diag, alpha, biash, qh, khp, vt);
    // 4) MFMA flash attention (writes bf16 hi/lo split directly)
    flash_mfma<<<dim3(S_ / 64, B_ * H_), 256, 0, stream>>>(
        qh, khp, vt, mask, a_hi, a_lo);
    // 5) out = attn @ Wout + bout  (3-term bf16 MFMA, shared staging)
    gemm_t<3, false><<<dim3(E_ / 128, M_ / 128), 256, 0, stream>>>(
        a_hi, a_lo, wo_hi, wo_lo, bout, out, M_, E_, E_);
}

// Round 7
// 308.066 us; speedup vs baseline: 6.6042x; 1.0465x over previous
//
#include <hip/hip_runtime.h>
#include <hip/hip_bf16.h>
#include <cmath>

#define B_ 2
#define S_ 2048
#define E_ 1024
#define H_ 16
#define M_ (B_*S_)    // 4096
#define N3_ (3*E_)    // 3072

typedef unsigned short u16;
typedef unsigned int u32;
typedef __attribute__((ext_vector_type(8))) short bf16x8;     // 8x16b = 4 VGPRs
typedef __attribute__((ext_vector_type(8))) _Float16 f16x8;
typedef __attribute__((ext_vector_type(4))) float f32x4;

// hardware exp2 (v_exp_f32) — avoid __exp2f which collides with glibc macros
__device__ __forceinline__ float hw_exp2(float x) {
    return __builtin_amdgcn_exp2f(x);
}
__device__ __forceinline__ u16 cvt_bf(float x) {              // HW RNE cvt
    return __builtin_bit_cast(u16, __float2bfloat16(x));
}
__device__ __forceinline__ float bf2f(u16 h) {
    return __uint_as_float((u32)h << 16);
}
__device__ __forceinline__ u16 f2h(float x) {
    _Float16 h = (_Float16)x;
    return __builtin_bit_cast(u16, h);
}
__device__ __forceinline__ float h2f(u16 b) {
    return (float)__builtin_bit_cast(_Float16, b);
}
__device__ __forceinline__ void gld_lds16(const void* g, void* l) {
    __builtin_amdgcn_global_load_lds((const __attribute__((address_space(1))) void*)g,
                                     (__attribute__((address_space(3))) void*)l, 16, 0, 0);
}

template<bool F16>
__device__ __forceinline__ f32x4 mma16(bf16x8 a, bf16x8 b, f32x4 c) {
    if constexpr (F16)
        return __builtin_amdgcn_mfma_f32_16x16x32_f16(
            __builtin_bit_cast(f16x8, a), __builtin_bit_cast(f16x8, b), c, 0, 0, 0);
    else
        return __builtin_amdgcn_mfma_f32_16x16x32_bf16(a, b, c, 0, 0, 0);
}

// ---------------------------------------------------------------------------
// x (f32) -> fp16 hi/lo split (same layout)
// ---------------------------------------------------------------------------
__global__ __launch_bounds__(256)
void split_a_f16(const float* __restrict__ in, u16* __restrict__ hi, u16* __restrict__ lo, int n4)
{
    int i = blockIdx.x * 256 + threadIdx.x;
    if (i >= n4) return;
    float4 v = ((const float4*)in)[i];
    float vv[4] = {v.x, v.y, v.z, v.w};
    u16 h[4], l[4];
    #pragma unroll
    for (int j = 0; j < 4; j++) {
        h[j] = f2h(vv[j]);
        l[j] = f2h(vv[j] - h2f(h[j]));
    }
    ((uint2*)hi)[i] = make_uint2((u32)h[0] | ((u32)h[1] << 16), (u32)h[2] | ((u32)h[3] << 16));
    ((uint2*)lo)[i] = make_uint2((u32)l[0] | ((u32)l[1] << 16), (u32)l[2] | ((u32)l[3] << 16));
}

// ---------------------------------------------------------------------------
// LDS-tiled transpose splits: W [K][N] f32 -> B^T [N][K] (coalesced both sides)
// ---------------------------------------------------------------------------
__global__ __launch_bounds__(256)
void split_bt_f16hi(const float* __restrict__ W, u16* __restrict__ hi, int K, int N)
{
    __shared__ float tile[64][65];
    const int tid = threadIdx.x;
    const int kb = blockIdx.y * 64, nb = blockIdx.x * 64;
    const int c = tid & 63, r0 = tid >> 6;
    #pragma unroll
    for (int i = 0; i < 16; i++) {
        int r = r0 + i * 4;
        tile[r][c] = W[(size_t)(kb + r) * N + nb + c];
    }
    __syncthreads();
    #pragma unroll
    for (int i = 0; i < 16; i++) {
        int n = r0 + i * 4;
        hi[(size_t)(nb + n) * K + kb + c] = f2h(tile[c][n]);
    }
}

__global__ __launch_bounds__(256)
void split_bt(const float* __restrict__ W, u16* __restrict__ hi, u16* __restrict__ lo,
              int K, int N)
{
    __shared__ float tile[64][65];
    const int tid = threadIdx.x;
    const int kb = blockIdx.y * 64, nb = blockIdx.x * 64;
    const int c = tid & 63, r0 = tid >> 6;
    #pragma unroll
    for (int i = 0; i < 16; i++) {
        int r = r0 + i * 4;
        tile[r][c] = W[(size_t)(kb + r) * N + nb + c];
    }
    __syncthreads();
    #pragma unroll
    for (int i = 0; i < 16; i++) {
        int n = r0 + i * 4;
        float v = tile[c][n];
        u16 h = cvt_bf(v);
        u16 l = cvt_bf(v - bf2f(h));
        size_t o = (size_t)(nb + n) * K + kb + c;
        hi[o] = h; lo[o] = l;
    }
}

// ---------------------------------------------------------------------------
// Multi-term split GEMM, double-buffered, single barrier per K-block (T3-min):
//   NT=2 (fp16):  C = Ah@Bh + Al@Bh + bias          (48KB LDS dbuf)
//   NT=3 (bf16):  C = Ah@Bh + Al@Bh + Ah@Bl + bias  (64KB LDS dbuf)
// 128x128 tile, BK=32, 4 waves (2x2). Chunk-XOR swizzle ((r>>1)&3) -> 2-way
// (free) bank access on ds_read_b128. Bh/Ah fragments reused across passes.
// ---------------------------------------------------------------------------
template<int NT, bool F16>
__global__ __launch_bounds__(256, 2)
void gemm_t(const u16* __restrict__ Ahi, const u16* __restrict__ Alo,
            const u16* __restrict__ Bhi, const u16* __restrict__ Blo,
            const float* __restrict__ bias, float* __restrict__ C,
            int M, int N, int K)
{
    __shared__ u16 smem[2][(NT + 1) * 4096];   // dbuf x (NT+1) tiles of 128x32
    const int tid = threadIdx.x;
    const int lane = tid & 63;
    const int w = tid >> 6;
    const int wr = w >> 1, wc = w & 1;
    const int l15 = lane & 15, g = lane >> 4;
    const int bm = blockIdx.y * 128;
    const int bn = blockIdx.x * 128;
    const int rsw = ((l15 >> 1) & 3) << 3;     // read-side chunk XOR (u16 units)
    const f32x4 z4 = {0.f, 0.f, 0.f, 0.f};
    f32x4 acc[4][4];
    #pragma unroll
    for (int m = 0; m < 4; m++)
        #pragma unroll
        for (int n = 0; n < 4; n++) acc[m][n] = z4;

    auto stage = [&](int bi, int ko) {
        #pragma unroll
        for (int ti = 0; ti < NT + 1; ti++) {
            const u16* base = (ti == 0) ? Ahi : (ti == 1) ? Alo : (ti == 2) ? Bhi : Blo;
            const int rb = (ti < 2) ? bm : bn;
            #pragma unroll
            for (int u = 0; u < 2; u++) {
                int c_ = u * 256 + tid;                    // 0..511 chunks of 16B
                int r = c_ >> 2;
                int cs = ((c_ & 3) ^ ((r >> 1) & 3)) << 3; // pre-swizzled src col
                gld_lds16(base + (size_t)(rb + r) * K + ko + cs,
                          (char*)&smem[bi][ti * 4096] + ((c_ >> 6) << 10));
            }
        }
    };

    stage(0, 0);
    __syncthreads();
    const int niter = K >> 5;
    for (int i = 0; i < niter; i++) {
        const int cur = i & 1;
        if (i + 1 < niter) stage(cur ^ 1, (i + 1) << 5);
        const u16* sA  = &smem[cur][0];
        const u16* sAl = &smem[cur][4096];
        const u16* sB  = &smem[cur][8192];
        const u16* sBl = &smem[cur][12288];
        bf16x8 ah[4], bh[4], al[4];
        #pragma unroll
        for (int n = 0; n < 4; n++)
            bh[n] = *(const bf16x8*)&sB[(wc*64 + n*16 + l15)*32 + ((g << 3) ^ rsw)];
        #pragma unroll
        for (int m = 0; m < 4; m++)
            ah[m] = *(const bf16x8*)&sA[(wr*64 + m*16 + l15)*32 + ((g << 3) ^ rsw)];
        #pragma unroll
        for (int m = 0; m < 4; m++)
            #pragma unroll
            for (int n = 0; n < 4; n++)
                acc[m][n] = mma16<F16>(ah[m], bh[n], acc[m][n]);
        #pragma unroll
        for (int m = 0; m < 4; m++)
            al[m] = *(const bf16x8*)&sAl[(wr*64 + m*16 + l15)*32 + ((g << 3) ^ rsw)];
        #pragma unroll
        for (int m = 0; m < 4; m++)
            #pragma unroll
            for (int n = 0; n < 4; n++)
                acc[m][n] = mma16<F16>(al[m], bh[n], acc[m][n]);
        if constexpr (NT == 3) {
            bf16x8 bl[4];
            #pragma unroll
            for (int n = 0; n < 4; n++)
                bl[n] = *(const bf16x8*)&sBl[(wc*64 + n*16 + l15)*32 + ((g << 3) ^ rsw)];
            #pragma unroll
            for (int m = 0; m < 4; m++)
                #pragma unroll
                for (int n = 0; n < 4; n++)
                    acc[m][n] = mma16<F16>(ah[m], bl[n], acc[m][n]);
        }
        __syncthreads();    // drains next-tile loads (hidden) + read-safety
    }
    // epilogue: C/D layout col=lane&15, row=(lane>>4)*4+reg
    #pragma unroll
    for (int m = 0; m < 4; m++) {
        #pragma unroll
        for (int n = 0; n < 4; n++) {
            int col = bn + wc*64 + n*16 + l15;
            float bv = bias[col];
            #pragma unroll
            for (int r = 0; r < 4; r++) {
                int row = bm + wr*64 + m*16 + g*4 + r;
                C[(size_t)row * N + col] = acc[m][n][r] + bv;
            }
        }
    }
}

// ---------------------------------------------------------------------------
// Normalized FWHT over 64 lanes via shuffle butterflies.
// ---------------------------------------------------------------------------
__device__ __forceinline__ float fwht64(float x, int lane)
{
    #pragma unroll
    for (int h = 1; h < 64; h <<= 1) {
        float y = __shfl_xor(x, h, 64);
        x = (lane & h) ? (y - x) : (x + y);
    }
    return x * 0.125f;
}

// qkv f32 -> transformed q,k (b,h,s,d) bf16 and v^T (b,h,d,s) bf16.
__global__ __launch_bounds__(256)
void transform_split(const float* __restrict__ qkv, const float* __restrict__ diag,
                     const float* __restrict__ alphap, const float* __restrict__ biasp,
                     u16* __restrict__ qh, u16* __restrict__ kh, u16* __restrict__ vt)
{
    const int lane = threadIdx.x & 63;
    const int w = (blockIdx.x * 256 + threadIdx.x) >> 6;
    const int h = w & (H_ - 1);
    const int s = (w >> 4) & (S_ - 1);
    const int b = w >> 15;
    const int bh = b * H_ + h;
    const float alpha = alphap[0];
    const float dg = diag[lane];
    const float bb = biasp[lane];
    const float* row = qkv + (size_t)(b * S_ + s) * N3_;
    const size_t o = ((size_t)bh * S_ + s) * 64 + lane;

    float xq = row[h*64 + lane];
    float t = fwht64(fwht64(xq, lane) * dg, lane);
    qh[o] = cvt_bf(xq + alpha * t + bb);
    float xk = row[E_ + h*64 + lane];
    t = fwht64(fwht64(xk, lane) * dg, lane);
    kh[o] = cvt_bf(xk + alpha * t + bb);
    vt[((size_t)bh * 64 + lane) * S_ + s] = cvt_bf(row[2*E_ + h*64 + lane]);
}

// ---------------------------------------------------------------------------
// MFMA flash attention v3:
//  - double-buffered K/V, ONE __syncthreads per tile (stage-ahead pipeline)
//  - exp2-domain online softmax (scale*log2e folded into mask FMA), m_i init
//    6.0 (log2 units) -> defer-rescale almost never fires, stays general
//  - HW cvt P-pack; s_setprio(1) around MFMA clusters (T5)
//  - swapped QK^T / PV-as-O^T, XOR-swizzled tiles (as r4)
// ---------------------------------------------------------------------------
__global__ __launch_bounds__(256)
void flash_mfma(const u16* __restrict__ qh, const u16* __restrict__ kh,
                const u16* __restrict__ vt, const int* __restrict__ mask,
                u16* __restrict__ ohi, u16* __restrict__ olo)
{
    __shared__ u16 Ks[2][64*64];     // [key][d], XOR-swizzled
    __shared__ u16 Vs[2][64*64];     // [d][key], XOR-swizzled
    __shared__ u16 Ps[4][16*72];     // wave-private P [q=l15][key], pad 72
    __shared__ float smask[S_];      // additive mask bias (0 or -3e38)
    const int tid = threadIdx.x;
    const int lane = tid & 63;
    const int w = tid >> 6;
    const int l15 = lane & 15, g = lane >> 4;
    const int bh = blockIdx.y;
    const int b = bh >> 4, h = bh & 15;
    const int q0 = blockIdx.x * 64;
    const u16* qb = qh + (size_t)bh * S_ * 64;
    const u16* kb = kh + (size_t)bh * S_ * 64;
    const u16* vb = vt + (size_t)bh * 64 * S_;
    const float SCALE2 = 0.18033688011112f;   // 0.125 * log2(e)

    #pragma unroll
    for (int i = 0; i < S_/256; i++)
        smask[i*256 + tid] = mask[b*S_ + i*256 + tid] ? 0.f : -3.0e38f;

    bf16x8 qf0, qf1;
    {
        const u16* qr = qb + (size_t)(q0 + w*16 + l15) * 64 + g*8;
        qf0 = *(const bf16x8*)qr;
        qf1 = *(const bf16x8*)(qr + 32);
    }
    const f32x4 z4 = {0.f, 0.f, 0.f, 0.f};
    float m_i = 6.0f, l_i = 0.f;     // log2-domain running max; high init = defer
    f32x4 acc[4];
    #pragma unroll
    for (int n = 0; n < 4; n++) acc[n] = z4;

    const int swz = (l15 & 7) << 3;

    auto stage_kv = [&](int bi, int tt) {
        const int kk0 = tt * 64;
        #pragma unroll
        for (int u = 0; u < 2; u++) {
            int f = u * 256 + tid;
            int r = f >> 3;
            int cs = ((f & 7) ^ (r & 7)) * 8;
            gld_lds16(kb + (size_t)(kk0 + r) * 64 + cs, (char*)&Ks[bi][0] + ((f >> 6) << 10));
            gld_lds16(vb + (size_t)r * S_ + kk0 + cs,   (char*)&Vs[bi][0] + ((f >> 6) << 10));
        }
    };

    stage_kv(0, 0);
    __syncthreads();                             // tile 0 + smask ready

    for (int t = 0; t < S_/64; t++) {
        const int cur = t & 1;
        if (t + 1 < S_/64) stage_kv(cur ^ 1, t + 1);   // issue-ahead (hidden)
        const int k0 = t * 64;

        // S^T = K @ Q
        f32x4 sv[4];
        __builtin_amdgcn_s_setprio(1);
        #pragma unroll
        for (int nt = 0; nt < 4; nt++) {
            int row = nt*16 + l15;
            bf16x8 ka0 = *(const bf16x8*)&Ks[cur][(row*64 +  0 + g*8) ^ swz];
            bf16x8 ka1 = *(const bf16x8*)&Ks[cur][(row*64 + 32 + g*8) ^ swz];
            sv[nt] = __builtin_amdgcn_mfma_f32_16x16x32_bf16(ka0, qf0, z4, 0, 0, 0);
            sv[nt] = __builtin_amdgcn_mfma_f32_16x16x32_bf16(ka1, qf1, sv[nt], 0, 0, 0);
        }
        __builtin_amdgcn_s_setprio(0);
        // scale to log2 domain + additive mask bias
        #pragma unroll
        for (int nt = 0; nt < 4; nt++) {
            float4 mb = *(const float4*)&smask[k0 + nt*16 + g*4];
            sv[nt][0] = fmaf(sv[nt][0], SCALE2, mb.x);
            sv[nt][1] = fmaf(sv[nt][1], SCALE2, mb.y);
            sv[nt][2] = fmaf(sv[nt][2], SCALE2, mb.z);
            sv[nt][3] = fmaf(sv[nt][3], SCALE2, mb.w);
        }
        // online softmax (per-lane scalar state, q = l15)
        float rm = fmaxf(fmaxf(sv[0][0], sv[0][1]), fmaxf(sv[0][2], sv[0][3]));
        #pragma unroll
        for (int nt = 1; nt < 4; nt++) {
            rm = fmaxf(rm, fmaxf(sv[nt][0], sv[nt][1]));
            rm = fmaxf(rm, fmaxf(sv[nt][2], sv[nt][3]));
        }
        rm = fmaxf(rm, __shfl_xor(rm, 16, 64));
        rm = fmaxf(rm, __shfl_xor(rm, 32, 64));
        const int grow = __any(rm > m_i);
        float mn = m_i, fsc = 1.f;
        if (grow) {
            mn = fmaxf(m_i, rm);
            fsc = hw_exp2(m_i - mn);
            m_i = mn;
        }
        float rs = 0.f;
        #pragma unroll
        for (int nt = 0; nt < 4; nt++)
            #pragma unroll
            for (int r = 0; r < 4; r++) {
                float p = hw_exp2(sv[nt][r] - mn);
                sv[nt][r] = p;
                rs += p;
            }
        rs += __shfl_xor(rs, 16, 64);
        rs += __shfl_xor(rs, 32, 64);
        if (grow) {
            l_i = l_i * fsc + rs;
            #pragma unroll
            for (int n = 0; n < 4; n++)
                #pragma unroll
                for (int r = 0; r < 4; r++) acc[n][r] *= fsc;
        } else {
            l_i += rs;
        }
        // pack P -> wave-private LDS (HW cvt)
        #pragma unroll
        for (int nt = 0; nt < 4; nt++) {
            u32 p01 = (u32)cvt_bf(sv[nt][0]) | ((u32)cvt_bf(sv[nt][1]) << 16);
            u32 p23 = (u32)cvt_bf(sv[nt][2]) | ((u32)cvt_bf(sv[nt][3]) << 16);
            *(uint2*)&Ps[w][l15*72 + nt*16 + g*4] = make_uint2(p01, p23);
        }
        asm volatile("s_waitcnt lgkmcnt(0)" ::: "memory");
        __builtin_amdgcn_sched_barrier(0);
        // O^T += V^T @ P^T
        __builtin_amdgcn_s_setprio(1);
        #pragma unroll
        for (int kc = 0; kc < 2; kc++) {
            bf16x8 pb = *(const bf16x8*)&Ps[w][l15*72 + kc*32 + g*8];
            #pragma unroll
            for (int nd = 0; nd < 4; nd++) {
                int row = nd*16 + l15;
                bf16x8 vf = *(const bf16x8*)&Vs[cur][(row*64 + kc*32 + g*8) ^ swz];
                acc[nd] = __builtin_amdgcn_mfma_f32_16x16x32_bf16(vf, pb, acc[nd], 0, 0, 0);
            }
        }
        __builtin_amdgcn_s_setprio(0);
        __syncthreads();                 // next tile staged+visible; buffers safe
    }
    // epilogue: emit bf16 hi/lo split (A-operand of out-GEMM)
    float inv = l_i > 0.f ? 1.f / l_i : 0.f;
    const int q = q0 + w*16 + l15;
    const size_t rowoff = (size_t)(b * S_ + q) * E_ + h*64;
    #pragma unroll
    for (int nd = 0; nd < 4; nd++) {
        #pragma unroll
        for (int r = 0; r < 4; r += 2) {
            float o0 = acc[nd][r]     * inv;
            float o1 = acc[nd][r + 1] * inv;
            u16 h0 = cvt_bf(o0), h1 = cvt_bf(o1);
            u16 lo0 = cvt_bf(o0 - bf2f(h0)), lo1 = cvt_bf(o1 - bf2f(h1));
            int col = nd*16 + g*4 + r;
            *(u32*)&ohi[rowoff + col] = (u32)h0 | ((u32)h1 << 16);
            *(u32*)&olo[rowoff + col] = (u32)lo0 | ((u32)lo1 << 16);
        }
    }
}

// ---------------------------------------------------------------------------
extern "C" void kernel_launch(void* const* d_in, const int* in_sizes, int n_in,
                              void* d_out, int out_size, void* d_ws, size_t ws_size,
                              hipStream_t stream)
{
    (void)in_sizes; (void)n_in; (void)out_size; (void)ws_size;
    const float* x     = (const float*)d_in[0];
    const int*   mask  = (const int*)  d_in[1];
    const float* Wqkv  = (const float*)d_in[2];
    const float* bqkv  = (const float*)d_in[3];
    const float* Wout  = (const float*)d_in[4];
    const float* bout  = (const float*)d_in[5];
    const float* diag  = (const float*)d_in[6];
    const float* alpha = (const float*)d_in[7];
    const float* biash = (const float*)d_in[8];
    float* out = (float*)d_out;

    // Workspace map (bytes). Peak 96.5 MB.
    char* ws = (char*)d_ws;
    float* qkv  = (float*)(ws + 0);            // 50,331,648 (f32 4096x3072)
    u16* wq_hi  = (u16*)(ws + 50331648);       //  6,291,456 (Wqkv^T fp16) } dead after gemm1
    u16* qh     = (u16*)(ws + 50331648);       //  8,388,608 (overlays wq_hi after gemm1)
    u16* khp    = (u16*)(ws + 58720256);       //  8,388,608
    u16* vt     = (u16*)(ws + 67108864);       //  8,388,608
    u16* x_hi   = (u16*)(ws + 75497472);       //  8,388,608 } x fp16 split for gemm1;
    u16* x_lo   = (u16*)(ws + 83886080);       //  8,388,608 } reused as attn bf16 hi/lo
    u16* a_hi   = x_hi;
    u16* a_lo   = x_lo;
    u16* wo_hi  = (u16*)(ws + 92274688);       //  2,097,152 (Wout^T bf16 hi)
    u16* wo_lo  = (u16*)(ws + 94371840);       //  2,097,152  [end 96,468,992]

    // 1) splits
    split_a_f16<<<4096, 256, 0, stream>>>(x, x_hi, x_lo, M_ * E_ / 4);
    split_bt_f16hi<<<dim3(N3_/64, E_/64), 256, 0, stream>>>(Wqkv, wq_hi, E_, N3_);
    split_bt<<<dim3(E_/64, E_/64), 256, 0, stream>>>(Wout, wo_hi, wo_lo, E_, E_);
    // 2) qkv = x @ Wqkv + bqkv  (2-term fp16 MFMA, dbuf pipeline)
    gemm_t<2, true><<<dim3(N3_ / 128, M_ / 128), 256, 0, stream>>>(
        x_hi, x_lo, wq_hi, wq_hi, bqkv, qkv, M_, N3_, E_);
    // 3) FWHT transform, split heads, emit bf16 q,k and v^T
    transform_split<<<(B_ * S_ * H_) / 4, 256, 0, stream>>>(
        qkv, diag, alpha, biash, qh, khp, vt);
    // 4) MFMA flash attention (writes bf16 hi/lo split directly)
    flash_mfma<<<dim3(S_ / 64, B_ * H_), 256, 0, stream>>>(
        qh, khp, vt, mask, a_hi, a_lo);
    // 5) out = attn @ Wout + bout  (3-term bf16 MFMA, dbuf pipeline)
    gemm_t<3, false><<<dim3(E_ / 128, M_ / 128), 256, 0, stream>>>(
        a_hi, a_lo, wo_hi, wo_lo, bout, out, M_, E_, E_);
}

// Round 8
// 305.244 us; speedup vs baseline: 6.6653x; 1.0092x over previous
//
#include <hip/hip_runtime.h>
#include <hip/hip_bf16.h>
#include <cmath>

#define B_ 2
#define S_ 2048
#define E_ 1024
#define H_ 16
#define M_ (B_*S_)    // 4096
#define N3_ (3*E_)    // 3072

typedef unsigned short u16;
typedef unsigned int u32;
typedef __attribute__((ext_vector_type(8))) short bf16x8;     // 8x16b = 4 VGPRs
typedef __attribute__((ext_vector_type(4))) short bf16x4;     // 4x16b = 2 VGPRs
typedef __attribute__((ext_vector_type(8))) _Float16 f16x8;
typedef __attribute__((ext_vector_type(4))) float f32x4;

// hardware exp2 (v_exp_f32) — avoid __exp2f which collides with glibc macros
__device__ __forceinline__ float hw_exp2(float x) {
    return __builtin_amdgcn_exp2f(x);
}
__device__ __forceinline__ u16 cvt_bf(float x) {              // HW RNE cvt
    return __builtin_bit_cast(u16, __float2bfloat16(x));
}
__device__ __forceinline__ float bf2f(u16 h) {
    return __uint_as_float((u32)h << 16);
}
__device__ __forceinline__ u16 f2h(float x) {
    _Float16 h = (_Float16)x;
    return __builtin_bit_cast(u16, h);
}
__device__ __forceinline__ float h2f(u16 b) {
    return (float)__builtin_bit_cast(_Float16, b);
}
__device__ __forceinline__ void gld_lds16(const void* g, void* l) {
    __builtin_amdgcn_global_load_lds((const __attribute__((address_space(1))) void*)g,
                                     (__attribute__((address_space(3))) void*)l, 16, 0, 0);
}

template<bool F16>
__device__ __forceinline__ f32x4 mma16(bf16x8 a, bf16x8 b, f32x4 c) {
    if constexpr (F16)
        return __builtin_amdgcn_mfma_f32_16x16x32_f16(
            __builtin_bit_cast(f16x8, a), __builtin_bit_cast(f16x8, b), c, 0, 0, 0);
    else
        return __builtin_amdgcn_mfma_f32_16x16x32_bf16(a, b, c, 0, 0, 0);
}

// ---------------------------------------------------------------------------
// x (f32) -> fp16 hi/lo split (same layout)
// ---------------------------------------------------------------------------
__global__ __launch_bounds__(256)
void split_a_f16(const float* __restrict__ in, u16* __restrict__ hi, u16* __restrict__ lo, int n4)
{
    int i = blockIdx.x * 256 + threadIdx.x;
    if (i >= n4) return;
    float4 v = ((const float4*)in)[i];
    float vv[4] = {v.x, v.y, v.z, v.w};
    u16 h[4], l[4];
    #pragma unroll
    for (int j = 0; j < 4; j++) {
        h[j] = f2h(vv[j]);
        l[j] = f2h(vv[j] - h2f(h[j]));
    }
    ((uint2*)hi)[i] = make_uint2((u32)h[0] | ((u32)h[1] << 16), (u32)h[2] | ((u32)h[3] << 16));
    ((uint2*)lo)[i] = make_uint2((u32)l[0] | ((u32)l[1] << 16), (u32)l[2] | ((u32)l[3] << 16));
}

// mask int -> additive bias float (0 or -3e38)
__global__ __launch_bounds__(256)
void mask2bias(const int* __restrict__ mask, float* __restrict__ mb, int n)
{
    int i = blockIdx.x * 256 + threadIdx.x;
    if (i < n) mb[i] = mask[i] ? 0.f : -3.0e38f;
}

// ---------------------------------------------------------------------------
// LDS-tiled transpose splits: W [K][N] f32 -> B^T [N][K] (coalesced both sides)
// ---------------------------------------------------------------------------
__global__ __launch_bounds__(256)
void split_bt_f16hi(const float* __restrict__ W, u16* __restrict__ hi, int K, int N)
{
    __shared__ float tile[64][65];
    const int tid = threadIdx.x;
    const int kb = blockIdx.y * 64, nb = blockIdx.x * 64;
    const int c = tid & 63, r0 = tid >> 6;
    #pragma unroll
    for (int i = 0; i < 16; i++) {
        int r = r0 + i * 4;
        tile[r][c] = W[(size_t)(kb + r) * N + nb + c];
    }
    __syncthreads();
    #pragma unroll
    for (int i = 0; i < 16; i++) {
        int n = r0 + i * 4;
        hi[(size_t)(nb + n) * K + kb + c] = f2h(tile[c][n]);
    }
}

__global__ __launch_bounds__(256)
void split_bt(const float* __restrict__ W, u16* __restrict__ hi, u16* __restrict__ lo,
              int K, int N)
{
    __shared__ float tile[64][65];
    const int tid = threadIdx.x;
    const int kb = blockIdx.y * 64, nb = blockIdx.x * 64;
    const int c = tid & 63, r0 = tid >> 6;
    #pragma unroll
    for (int i = 0; i < 16; i++) {
        int r = r0 + i * 4;
        tile[r][c] = W[(size_t)(kb + r) * N + nb + c];
    }
    __syncthreads();
    #pragma unroll
    for (int i = 0; i < 16; i++) {
        int n = r0 + i * 4;
        float v = tile[c][n];
        u16 h = cvt_bf(v);
        u16 l = cvt_bf(v - bf2f(h));
        size_t o = (size_t)(nb + n) * K + kb + c;
        hi[o] = h; lo[o] = l;
    }
}

// ---------------------------------------------------------------------------
// Multi-term split GEMM, double-buffered, single barrier per K-block
// (unchanged from round 7)
// ---------------------------------------------------------------------------
template<int NT, bool F16>
__global__ __launch_bounds__(256, 2)
void gemm_t(const u16* __restrict__ Ahi, const u16* __restrict__ Alo,
            const u16* __restrict__ Bhi, const u16* __restrict__ Blo,
            const float* __restrict__ bias, float* __restrict__ C,
            int M, int N, int K)
{
    __shared__ u16 smem[2][(NT + 1) * 4096];   // dbuf x (NT+1) tiles of 128x32
    const int tid = threadIdx.x;
    const int lane = tid & 63;
    const int w = tid >> 6;
    const int wr = w >> 1, wc = w & 1;
    const int l15 = lane & 15, g = lane >> 4;
    const int bm = blockIdx.y * 128;
    const int bn = blockIdx.x * 128;
    const int rsw = ((l15 >> 1) & 3) << 3;     // read-side chunk XOR (u16 units)
    const f32x4 z4 = {0.f, 0.f, 0.f, 0.f};
    f32x4 acc[4][4];
    #pragma unroll
    for (int m = 0; m < 4; m++)
        #pragma unroll
        for (int n = 0; n < 4; n++) acc[m][n] = z4;

    auto stage = [&](int bi, int ko) {
        #pragma unroll
        for (int ti = 0; ti < NT + 1; ti++) {
            const u16* base = (ti == 0) ? Ahi : (ti == 1) ? Alo : (ti == 2) ? Bhi : Blo;
            const int rb = (ti < 2) ? bm : bn;
            #pragma unroll
            for (int u = 0; u < 2; u++) {
                int c_ = u * 256 + tid;                    // 0..511 chunks of 16B
                int r = c_ >> 2;
                int cs = ((c_ & 3) ^ ((r >> 1) & 3)) << 3; // pre-swizzled src col
                gld_lds16(base + (size_t)(rb + r) * K + ko + cs,
                          (char*)&smem[bi][ti * 4096] + ((c_ >> 6) << 10));
            }
        }
    };

    stage(0, 0);
    __syncthreads();
    const int niter = K >> 5;
    for (int i = 0; i < niter; i++) {
        const int cur = i & 1;
        if (i + 1 < niter) stage(cur ^ 1, (i + 1) << 5);
        const u16* sA  = &smem[cur][0];
        const u16* sAl = &smem[cur][4096];
        const u16* sB  = &smem[cur][8192];
        const u16* sBl = &smem[cur][12288];
        bf16x8 ah[4], bh[4], al[4];
        #pragma unroll
        for (int n = 0; n < 4; n++)
            bh[n] = *(const bf16x8*)&sB[(wc*64 + n*16 + l15)*32 + ((g << 3) ^ rsw)];
        #pragma unroll
        for (int m = 0; m < 4; m++)
            ah[m] = *(const bf16x8*)&sA[(wr*64 + m*16 + l15)*32 + ((g << 3) ^ rsw)];
        #pragma unroll
        for (int m = 0; m < 4; m++)
            #pragma unroll
            for (int n = 0; n < 4; n++)
                acc[m][n] = mma16<F16>(ah[m], bh[n], acc[m][n]);
        #pragma unroll
        for (int m = 0; m < 4; m++)
            al[m] = *(const bf16x8*)&sAl[(wr*64 + m*16 + l15)*32 + ((g << 3) ^ rsw)];
        #pragma unroll
        for (int m = 0; m < 4; m++)
            #pragma unroll
            for (int n = 0; n < 4; n++)
                acc[m][n] = mma16<F16>(al[m], bh[n], acc[m][n]);
        if constexpr (NT == 3) {
            bf16x8 bl[4];
            #pragma unroll
            for (int n = 0; n < 4; n++)
                bl[n] = *(const bf16x8*)&sBl[(wc*64 + n*16 + l15)*32 + ((g << 3) ^ rsw)];
            #pragma unroll
            for (int m = 0; m < 4; m++)
                #pragma unroll
                for (int n = 0; n < 4; n++)
                    acc[m][n] = mma16<F16>(ah[m], bl[n], acc[m][n]);
        }
        __syncthreads();    // drains next-tile loads (hidden) + read-safety
    }
    // epilogue: C/D layout col=lane&15, row=(lane>>4)*4+reg
    #pragma unroll
    for (int m = 0; m < 4; m++) {
        #pragma unroll
        for (int n = 0; n < 4; n++) {
            int col = bn + wc*64 + n*16 + l15;
            float bv = bias[col];
            #pragma unroll
            for (int r = 0; r < 4; r++) {
                int row = bm + wr*64 + m*16 + g*4 + r;
                C[(size_t)row * N + col] = acc[m][n][r] + bv;
            }
        }
    }
}

// ---------------------------------------------------------------------------
// Normalized FWHT over 64 lanes via shuffle butterflies.
// ---------------------------------------------------------------------------
__device__ __forceinline__ float fwht64(float x, int lane)
{
    #pragma unroll
    for (int h = 1; h < 64; h <<= 1) {
        float y = __shfl_xor(x, h, 64);
        x = (lane & h) ? (y - x) : (x + y);
    }
    return x * 0.125f;
}

// qkv f32 -> transformed q,k (b,h,s,d) bf16 and v^T (b,h,d,s) bf16.
__global__ __launch_bounds__(256)
void transform_split(const float* __restrict__ qkv, const float* __restrict__ diag,
                     const float* __restrict__ alphap, const float* __restrict__ biasp,
                     u16* __restrict__ qh, u16* __restrict__ kh, u16* __restrict__ vt)
{
    const int lane = threadIdx.x & 63;
    const int w = (blockIdx.x * 256 + threadIdx.x) >> 6;
    const int h = w & (H_ - 1);
    const int s = (w >> 4) & (S_ - 1);
    const int b = w >> 15;
    const int bh = b * H_ + h;
    const float alpha = alphap[0];
    const float dg = diag[lane];
    const float bb = biasp[lane];
    const float* row = qkv + (size_t)(b * S_ + s) * N3_;
    const size_t o = ((size_t)bh * S_ + s) * 64 + lane;

    float xq = row[h*64 + lane];
    float t = fwht64(fwht64(xq, lane) * dg, lane);
    qh[o] = cvt_bf(xq + alpha * t + bb);
    float xk = row[E_ + h*64 + lane];
    t = fwht64(fwht64(xk, lane) * dg, lane);
    kh[o] = cvt_bf(xk + alpha * t + bb);
    vt[((size_t)bh * 64 + lane) * S_ + s] = cvt_bf(row[2*E_ + h*64 + lane]);
}

// ---------------------------------------------------------------------------
// MFMA flash attention v4:
//  - LDS = K/V dbuf ONLY (32 KB) -> 4-5 blocks/CU (was 2 at 50 KB)
//  - P stays IN REGISTERS: PV via mfma_f32_16x16x16bf16_1k whose B-fragment
//    (col=l15, k=g*4+j) is exactly the per-lane sv[nt][0..3] scores.
//    No Ps LDS, no shuffles, no lgkmcnt(0) serialization.
//  - mask bias from a small global array, 4x float4 per tile, issued BEFORE
//    staging so counted vmcnt keeps prefetch in flight
//  - exp2-domain softmax, defer-rescale, setprio, dbuf single-barrier (as r7)
// ---------------------------------------------------------------------------
__global__ __launch_bounds__(256, 4)
void flash_mfma(const u16* __restrict__ qh, const u16* __restrict__ kh,
                const u16* __restrict__ vt, const float* __restrict__ mbias,
                u16* __restrict__ ohi, u16* __restrict__ olo)
{
    __shared__ u16 Ks[2][64*64];     // [key][d], XOR-swizzled (granule ^ row&7)
    __shared__ u16 Vs[2][64*64];     // [d][key], XOR-swizzled
    const int tid = threadIdx.x;
    const int lane = tid & 63;
    const int w = tid >> 6;
    const int l15 = lane & 15, g = lane >> 4;
    const int g1 = g & 1, gh = g >> 1;
    const int sx = l15 & 7;
    const int bh = blockIdx.y;
    const int b = bh >> 4;
    const int q0 = blockIdx.x * 64;
    const u16* qb = qh + (size_t)bh * S_ * 64;
    const u16* kb = kh + (size_t)bh * S_ * 64;
    const u16* vb = vt + (size_t)bh * 64 * S_;
    const float* mrow = mbias + b * S_;
    const float SCALE2 = 0.18033688011112f;   // 0.125 * log2(e)

    // Q fragments pinned in registers (B-operand: col=q=l15, k=d)
    bf16x8 qf0, qf1;
    {
        const u16* qr = qb + (size_t)(q0 + w*16 + l15) * 64 + g*8;
        qf0 = *(const bf16x8*)qr;
        qf1 = *(const bf16x8*)(qr + 32);
    }
    const f32x4 z4 = {0.f, 0.f, 0.f, 0.f};
    float m_i = 6.0f, l_i = 0.f;     // log2-domain running max; high init = defer
    f32x4 acc[4];                    // O^T: acc[nd][r] = O[q=l15][d=nd*16+g*4+r]
    #pragma unroll
    for (int n = 0; n < 4; n++) acc[n] = z4;

    const int swz = sx << 3;         // u16-index XOR for b128 reads

    auto stage_kv = [&](int bi, int tt) {
        const int kk0 = tt * 64;
        #pragma unroll
        for (int u = 0; u < 2; u++) {
            int f = u * 256 + tid;
            int r = f >> 3;
            int cs = ((f & 7) ^ (r & 7)) * 8;
            gld_lds16(kb + (size_t)(kk0 + r) * 64 + cs, (char*)&Ks[bi][0] + ((f >> 6) << 10));
            gld_lds16(vb + (size_t)r * S_ + kk0 + cs,   (char*)&Vs[bi][0] + ((f >> 6) << 10));
        }
    };

    stage_kv(0, 0);
    __syncthreads();                             // tile 0 staged + visible

    for (int t = 0; t < S_/64; t++) {
        const int cur = t & 1;
        const int k0 = t * 64;
        // mask bias for THIS tile — issued before stage so its vmcnt wait
        // leaves the prefetch loads in flight (counted wait)
        float4 mb[4];
        #pragma unroll
        for (int nt = 0; nt < 4; nt++)
            mb[nt] = *(const float4*)&mrow[k0 + nt*16 + g*4];
        if (t + 1 < S_/64) stage_kv(cur ^ 1, t + 1);   // issue-ahead (hidden)

        // S^T = K @ Q  (C/D: col=q=l15, row(key)=g*4+r per nt)
        f32x4 sv[4];
        __builtin_amdgcn_s_setprio(1);
        #pragma unroll
        for (int nt = 0; nt < 4; nt++) {
            int row = nt*16 + l15;
            bf16x8 ka0 = *(const bf16x8*)&Ks[cur][(row*64 +  0 + g*8) ^ swz];
            bf16x8 ka1 = *(const bf16x8*)&Ks[cur][(row*64 + 32 + g*8) ^ swz];
            sv[nt] = __builtin_amdgcn_mfma_f32_16x16x32_bf16(ka0, qf0, z4, 0, 0, 0);
            sv[nt] = __builtin_amdgcn_mfma_f32_16x16x32_bf16(ka1, qf1, sv[nt], 0, 0, 0);
        }
        __builtin_amdgcn_s_setprio(0);
        // scale to log2 domain + additive mask bias
        #pragma unroll
        for (int nt = 0; nt < 4; nt++) {
            sv[nt][0] = fmaf(sv[nt][0], SCALE2, mb[nt].x);
            sv[nt][1] = fmaf(sv[nt][1], SCALE2, mb[nt].y);
            sv[nt][2] = fmaf(sv[nt][2], SCALE2, mb[nt].z);
            sv[nt][3] = fmaf(sv[nt][3], SCALE2, mb[nt].w);
        }
        // online softmax (per-lane scalar state, q = l15)
        float rm = fmaxf(fmaxf(sv[0][0], sv[0][1]), fmaxf(sv[0][2], sv[0][3]));
        #pragma unroll
        for (int nt = 1; nt < 4; nt++) {
            rm = fmaxf(rm, fmaxf(sv[nt][0], sv[nt][1]));
            rm = fmaxf(rm, fmaxf(sv[nt][2], sv[nt][3]));
        }
        rm = fmaxf(rm, __shfl_xor(rm, 16, 64));
        rm = fmaxf(rm, __shfl_xor(rm, 32, 64));
        const int grow = __any(rm > m_i);
        float mn = m_i, fsc = 1.f;
        if (grow) {
            mn = fmaxf(m_i, rm);
            fsc = hw_exp2(m_i - mn);
            m_i = mn;
        }
        float rs = 0.f;
        #pragma unroll
        for (int nt = 0; nt < 4; nt++)
            #pragma unroll
            for (int r = 0; r < 4; r++) {
                float p = hw_exp2(sv[nt][r] - mn);
                sv[nt][r] = p;
                rs += p;
            }
        rs += __shfl_xor(rs, 16, 64);
        rs += __shfl_xor(rs, 32, 64);
        if (grow) {
            l_i = l_i * fsc + rs;
            #pragma unroll
            for (int n = 0; n < 4; n++)
                #pragma unroll
                for (int r = 0; r < 4; r++) acc[n][r] *= fsc;
        } else {
            l_i += rs;
        }
        // pack P to bf16x4 fragments — stays in registers
        bf16x4 pk[4];
        #pragma unroll
        for (int nt = 0; nt < 4; nt++) {
            uint2 q2 = make_uint2((u32)cvt_bf(sv[nt][0]) | ((u32)cvt_bf(sv[nt][1]) << 16),
                                  (u32)cvt_bf(sv[nt][2]) | ((u32)cvt_bf(sv[nt][3]) << 16));
            pk[nt] = __builtin_bit_cast(bf16x4, q2);
        }
        // O^T += V^T @ P^T via 16x16x16 (A: row=d, k=key=kk*16+g*4+j from LDS;
        // B: col=q=l15, k=g*4+j = pk[kk] in-register)
        __builtin_amdgcn_s_setprio(1);
        #pragma unroll
        for (int kk = 0; kk < 4; kk++) {
            #pragma unroll
            for (int nd = 0; nd < 4; nd++) {
                int addr = (nd*16 + l15)*64 + ((((kk<<1) + gh) ^ sx) << 3) + g1*4;
                bf16x4 vf = *(const bf16x4*)&Vs[cur][addr];
                acc[nd] = __builtin_amdgcn_mfma_f32_16x16x16bf16_1k(vf, pk[kk], acc[nd], 0, 0, 0);
            }
        }
        __builtin_amdgcn_s_setprio(0);
        __syncthreads();                 // next tile staged+visible; buffers safe
    }
    // epilogue: emit bf16 hi/lo split (A-operand of out-GEMM)
    float inv = l_i > 0.f ? 1.f / l_i : 0.f;
    const int q = q0 + w*16 + l15;
    const size_t rowoff = (size_t)(b * S_ + q) * E_ + (blockIdx.y & 15)*64;
    #pragma unroll
    for (int nd = 0; nd < 4; nd++) {
        #pragma unroll
        for (int r = 0; r < 4; r += 2) {
            float o0 = acc[nd][r]     * inv;
            float o1 = acc[nd][r + 1] * inv;
            u16 h0 = cvt_bf(o0), h1 = cvt_bf(o1);
            u16 lo0 = cvt_bf(o0 - bf2f(h0)), lo1 = cvt_bf(o1 - bf2f(h1));
            int col = nd*16 + g*4 + r;
            *(u32*)&ohi[rowoff + col] = (u32)h0 | ((u32)h1 << 16);
            *(u32*)&olo[rowoff + col] = (u32)lo0 | ((u32)lo1 << 16);
        }
    }
}

// ---------------------------------------------------------------------------
extern "C" void kernel_launch(void* const* d_in, const int* in_sizes, int n_in,
                              void* d_out, int out_size, void* d_ws, size_t ws_size,
                              hipStream_t stream)
{
    (void)in_sizes; (void)n_in; (void)out_size; (void)ws_size;
    const float* x     = (const float*)d_in[0];
    const int*   mask  = (const int*)  d_in[1];
    const float* Wqkv  = (const float*)d_in[2];
    const float* bqkv  = (const float*)d_in[3];
    const float* Wout  = (const float*)d_in[4];
    const float* bout  = (const float*)d_in[5];
    const float* diag  = (const float*)d_in[6];
    const float* alpha = (const float*)d_in[7];
    const float* biash = (const float*)d_in[8];
    float* out = (float*)d_out;

    // Workspace map (bytes). Peak 96.5 MB.
    char* ws = (char*)d_ws;
    float* qkv  = (float*)(ws + 0);            // 50,331,648 (f32 4096x3072)
    u16* wq_hi  = (u16*)(ws + 50331648);       //  6,291,456 (Wqkv^T fp16) } dead after gemm1
    u16* qh     = (u16*)(ws + 50331648);       //  8,388,608 (overlays wq_hi after gemm1)
    u16* khp    = (u16*)(ws + 58720256);       //  8,388,608
    u16* vt     = (u16*)(ws + 67108864);       //  8,388,608
    u16* x_hi   = (u16*)(ws + 75497472);       //  8,388,608 } x fp16 split for gemm1;
    u16* x_lo   = (u16*)(ws + 83886080);       //  8,388,608 } reused as attn bf16 hi/lo
    u16* a_hi   = x_hi;
    u16* a_lo   = x_lo;
    u16* wo_hi  = (u16*)(ws + 92274688);       //  2,097,152 (Wout^T bf16 hi)
    u16* wo_lo  = (u16*)(ws + 94371840);       //  2,097,152
    float* mbias= (float*)(ws + 96468992);     //     16,384 [end 96,485,376]

    // 1) splits + mask bias
    split_a_f16<<<4096, 256, 0, stream>>>(x, x_hi, x_lo, M_ * E_ / 4);
    split_bt_f16hi<<<dim3(N3_/64, E_/64), 256, 0, stream>>>(Wqkv, wq_hi, E_, N3_);
    split_bt<<<dim3(E_/64, E_/64), 256, 0, stream>>>(Wout, wo_hi, wo_lo, E_, E_);
    mask2bias<<<(B_*S_ + 255)/256, 256, 0, stream>>>(mask, mbias, B_*S_);
    // 2) qkv = x @ Wqkv + bqkv  (2-term fp16 MFMA, dbuf pipeline)
    gemm_t<2, true><<<dim3(N3_ / 128, M_ / 128), 256, 0, stream>>>(
        x_hi, x_lo, wq_hi, wq_hi, bqkv, qkv, M_, N3_, E_);
    // 3) FWHT transform, split heads, emit bf16 q,k and v^T
    transform_split<<<(B_ * S_ * H_) / 4, 256, 0, stream>>>(
        qkv, diag, alpha, biash, qh, khp, vt);
    // 4) MFMA flash attention (writes bf16 hi/lo split directly)
    flash_mfma<<<dim3(S_ / 64, B_ * H_), 256, 0, stream>>>(
        qh, khp, vt, mbias, a_hi, a_lo);
    // 5) out = attn @ Wout + bout  (3-term bf16 MFMA, dbuf pipeline)
    gemm_t<3, false><<<dim3(E_ / 128, M_ / 128), 256, 0, stream>>>(
        a_hi, a_lo, wo_hi, wo_lo, bout, out, M_, E_, E_);
}

// Round 10
// 291.488 us; speedup vs baseline: 6.9798x; 1.0472x over previous
//
#include <hip/hip_runtime.h>
#include <hip/hip_bf16.h>
#include <cmath>

#define B_ 2
#define S_ 2048
#define E_ 1024
#define H_ 16
#define M_ (B_*S_)    // 4096
#define N3_ (3*E_)    // 3072

typedef unsigned short u16;
typedef unsigned int u32;
typedef __attribute__((ext_vector_type(8))) short bf16x8;     // 8x16b = 4 VGPRs
typedef __attribute__((ext_vector_type(4))) short bf16x4;     // 4x16b = 2 VGPRs
typedef __attribute__((ext_vector_type(8))) _Float16 f16x8;
typedef __attribute__((ext_vector_type(4))) float f32x4;

// hardware exp2 (v_exp_f32) — avoid __exp2f which collides with glibc macros
__device__ __forceinline__ float hw_exp2(float x) {
    return __builtin_amdgcn_exp2f(x);
}
__device__ __forceinline__ u16 cvt_bf(float x) {              // HW RNE cvt
    return __builtin_bit_cast(u16, __float2bfloat16(x));
}
__device__ __forceinline__ float bf2f(u16 h) {
    return __uint_as_float((u32)h << 16);
}
__device__ __forceinline__ u16 f2h(float x) {
    _Float16 h = (_Float16)x;
    return __builtin_bit_cast(u16, h);
}
__device__ __forceinline__ float h2f(u16 b) {
    return (float)__builtin_bit_cast(_Float16, b);
}
__device__ __forceinline__ void gld_lds16(const void* g, void* l) {
    __builtin_amdgcn_global_load_lds((const __attribute__((address_space(1))) void*)g,
                                     (__attribute__((address_space(3))) void*)l, 16, 0, 0);
}

template<bool F16>
__device__ __forceinline__ f32x4 mma16(bf16x8 a, bf16x8 b, f32x4 c) {
    if constexpr (F16)
        return __builtin_amdgcn_mfma_f32_16x16x32_f16(
            __builtin_bit_cast(f16x8, a), __builtin_bit_cast(f16x8, b), c, 0, 0, 0);
    else
        return __builtin_amdgcn_mfma_f32_16x16x32_bf16(a, b, c, 0, 0, 0);
}

// ---------------------------------------------------------------------------
// x (f32) -> fp16 hi/lo split (same layout)
// ---------------------------------------------------------------------------
__global__ __launch_bounds__(256)
void split_a_f16(const float* __restrict__ in, u16* __restrict__ hi, u16* __restrict__ lo, int n4)
{
    int i = blockIdx.x * 256 + threadIdx.x;
    if (i >= n4) return;
    float4 v = ((const float4*)in)[i];
    float vv[4] = {v.x, v.y, v.z, v.w};
    u16 h[4], l[4];
    #pragma unroll
    for (int j = 0; j < 4; j++) {
        h[j] = f2h(vv[j]);
        l[j] = f2h(vv[j] - h2f(h[j]));
    }
    ((uint2*)hi)[i] = make_uint2((u32)h[0] | ((u32)h[1] << 16), (u32)h[2] | ((u32)h[3] << 16));
    ((uint2*)lo)[i] = make_uint2((u32)l[0] | ((u32)l[1] << 16), (u32)l[2] | ((u32)l[3] << 16));
}

// mask int -> additive bias float (0 or -3e38)
__global__ __launch_bounds__(256)
void mask2bias(const int* __restrict__ mask, float* __restrict__ mb, int n)
{
    int i = blockIdx.x * 256 + threadIdx.x;
    if (i < n) mb[i] = mask[i] ? 0.f : -3.0e38f;
}

// ---------------------------------------------------------------------------
// LDS-tiled transpose splits: W [K][N] f32 -> B^T [N][K] (coalesced both sides)
// ---------------------------------------------------------------------------
__global__ __launch_bounds__(256)
void split_bt_f16hi(const float* __restrict__ W, u16* __restrict__ hi, int K, int N)
{
    __shared__ float tile[64][65];
    const int tid = threadIdx.x;
    const int kb = blockIdx.y * 64, nb = blockIdx.x * 64;
    const int c = tid & 63, r0 = tid >> 6;
    #pragma unroll
    for (int i = 0; i < 16; i++) {
        int r = r0 + i * 4;
        tile[r][c] = W[(size_t)(kb + r) * N + nb + c];
    }
    __syncthreads();
    #pragma unroll
    for (int i = 0; i < 16; i++) {
        int n = r0 + i * 4;
        hi[(size_t)(nb + n) * K + kb + c] = f2h(tile[c][n]);
    }
}

__global__ __launch_bounds__(256)
void split_bt(const float* __restrict__ W, u16* __restrict__ hi, u16* __restrict__ lo,
              int K, int N)
{
    __shared__ float tile[64][65];
    const int tid = threadIdx.x;
    const int kb = blockIdx.y * 64, nb = blockIdx.x * 64;
    const int c = tid & 63, r0 = tid >> 6;
    #pragma unroll
    for (int i = 0; i < 16; i++) {
        int r = r0 + i * 4;
        tile[r][c] = W[(size_t)(kb + r) * N + nb + c];
    }
    __syncthreads();
    #pragma unroll
    for (int i = 0; i < 16; i++) {
        int n = r0 + i * 4;
        float v = tile[c][n];
        u16 h = cvt_bf(v);
        u16 l = cvt_bf(v - bf2f(h));
        size_t o = (size_t)(nb + n) * K + kb + c;
        hi[o] = h; lo[o] = l;
    }
}

// ---------------------------------------------------------------------------
// Multi-term split GEMM, double-buffered, single barrier per K-block
// (unchanged from round 8)
// ---------------------------------------------------------------------------
template<int NT, bool F16>
__global__ __launch_bounds__(256, 2)
void gemm_t(const u16* __restrict__ Ahi, const u16* __restrict__ Alo,
            const u16* __restrict__ Bhi, const u16* __restrict__ Blo,
            const float* __restrict__ bias, float* __restrict__ C,
            int M, int N, int K)
{
    __shared__ u16 smem[2][(NT + 1) * 4096];   // dbuf x (NT+1) tiles of 128x32
    const int tid = threadIdx.x;
    const int lane = tid & 63;
    const int w = tid >> 6;
    const int wr = w >> 1, wc = w & 1;
    const int l15 = lane & 15, g = lane >> 4;
    const int bm = blockIdx.y * 128;
    const int bn = blockIdx.x * 128;
    const int rsw = ((l15 >> 1) & 3) << 3;     // read-side chunk XOR (u16 units)
    const f32x4 z4 = {0.f, 0.f, 0.f, 0.f};
    f32x4 acc[4][4];
    #pragma unroll
    for (int m = 0; m < 4; m++)
        #pragma unroll
        for (int n = 0; n < 4; n++) acc[m][n] = z4;

    auto stage = [&](int bi, int ko) {
        #pragma unroll
        for (int ti = 0; ti < NT + 1; ti++) {
            const u16* base = (ti == 0) ? Ahi : (ti == 1) ? Alo : (ti == 2) ? Bhi : Blo;
            const int rb = (ti < 2) ? bm : bn;
            #pragma unroll
            for (int u = 0; u < 2; u++) {
                int c_ = u * 256 + tid;                    // 0..511 chunks of 16B
                int r = c_ >> 2;
                int cs = ((c_ & 3) ^ ((r >> 1) & 3)) << 3; // pre-swizzled src col
                gld_lds16(base + (size_t)(rb + r) * K + ko + cs,
                          (char*)&smem[bi][ti * 4096] + ((c_ >> 6) << 10));
            }
        }
    };

    stage(0, 0);
    __syncthreads();
    const int niter = K >> 5;
    for (int i = 0; i < niter; i++) {
        const int cur = i & 1;
        if (i + 1 < niter) stage(cur ^ 1, (i + 1) << 5);
        const u16* sA  = &smem[cur][0];
        const u16* sAl = &smem[cur][4096];
        const u16* sB  = &smem[cur][8192];
        const u16* sBl = &smem[cur][12288];
        bf16x8 ah[4], bh[4], al[4];
        #pragma unroll
        for (int n = 0; n < 4; n++)
            bh[n] = *(const bf16x8*)&sB[(wc*64 + n*16 + l15)*32 + ((g << 3) ^ rsw)];
        #pragma unroll
        for (int m = 0; m < 4; m++)
            ah[m] = *(const bf16x8*)&sA[(wr*64 + m*16 + l15)*32 + ((g << 3) ^ rsw)];
        #pragma unroll
        for (int m = 0; m < 4; m++)
            #pragma unroll
            for (int n = 0; n < 4; n++)
                acc[m][n] = mma16<F16>(ah[m], bh[n], acc[m][n]);
        #pragma unroll
        for (int m = 0; m < 4; m++)
            al[m] = *(const bf16x8*)&sAl[(wr*64 + m*16 + l15)*32 + ((g << 3) ^ rsw)];
        #pragma unroll
        for (int m = 0; m < 4; m++)
            #pragma unroll
            for (int n = 0; n < 4; n++)
                acc[m][n] = mma16<F16>(al[m], bh[n], acc[m][n]);
        if constexpr (NT == 3) {
            bf16x8 bl[4];
            #pragma unroll
            for (int n = 0; n < 4; n++)
                bl[n] = *(const bf16x8*)&sBl[(wc*64 + n*16 + l15)*32 + ((g << 3) ^ rsw)];
            #pragma unroll
            for (int m = 0; m < 4; m++)
                #pragma unroll
                for (int n = 0; n < 4; n++)
                    acc[m][n] = mma16<F16>(ah[m], bl[n], acc[m][n]);
        }
        __syncthreads();    // drains next-tile loads (hidden) + read-safety
    }
    // epilogue: C/D layout col=lane&15, row=(lane>>4)*4+reg
    #pragma unroll
    for (int m = 0; m < 4; m++) {
        #pragma unroll
        for (int n = 0; n < 4; n++) {
            int col = bn + wc*64 + n*16 + l15;
            float bv = bias[col];
            #pragma unroll
            for (int r = 0; r < 4; r++) {
                int row = bm + wr*64 + m*16 + g*4 + r;
                C[(size_t)row * N + col] = acc[m][n][r] + bv;
            }
        }
    }
}

// ---------------------------------------------------------------------------
// Normalized FWHT over 64 lanes via shuffle butterflies.
// ---------------------------------------------------------------------------
__device__ __forceinline__ float fwht64(float x, int lane)
{
    #pragma unroll
    for (int h = 1; h < 64; h <<= 1) {
        float y = __shfl_xor(x, h, 64);
        x = (lane & h) ? (y - x) : (x + y);
    }
    return x * 0.125f;
}

// qkv f32 -> transformed q,k (b,h,s,d) bf16 and v^T (b,h,d,s) bf16.
__global__ __launch_bounds__(256)
void transform_split(const float* __restrict__ qkv, const float* __restrict__ diag,
                     const float* __restrict__ alphap, const float* __restrict__ biasp,
                     u16* __restrict__ qh, u16* __restrict__ kh, u16* __restrict__ vt)
{
    const int lane = threadIdx.x & 63;
    const int w = (blockIdx.x * 256 + threadIdx.x) >> 6;
    const int h = w & (H_ - 1);
    const int s = (w >> 4) & (S_ - 1);
    const int b = w >> 15;
    const int bh = b * H_ + h;
    const float alpha = alphap[0];
    const float dg = diag[lane];
    const float bb = biasp[lane];
    const float* row = qkv + (size_t)(b * S_ + s) * N3_;
    const size_t o = ((size_t)bh * S_ + s) * 64 + lane;

    float xq = row[h*64 + lane];
    float t = fwht64(fwht64(xq, lane) * dg, lane);
    qh[o] = cvt_bf(xq + alpha * t + bb);
    float xk = row[E_ + h*64 + lane];
    t = fwht64(fwht64(xk, lane) * dg, lane);
    kh[o] = cvt_bf(xk + alpha * t + bb);
    vt[((size_t)bh * 64 + lane) * S_ + s] = cvt_bf(row[2*E_ + h*64 + lane]);
}

// ---------------------------------------------------------------------------
// MFMA flash attention v5:
//  - Q-tile 128 rows via 8 waves (512 threads): K/V staging instrs, barriers
//    and L2 K/V re-reads are amortized over 2x the q-rows. Per-wave structure
//    (16 q-rows, in-register P, 16x16x16 PV) IDENTICAL to v4.
//  - LDS = K/V dbuf only (32 KB); grid 512 blocks = 2 blocks/CU.
// ---------------------------------------------------------------------------
__global__ __launch_bounds__(512)
void flash_mfma(const u16* __restrict__ qh, const u16* __restrict__ kh,
                const u16* __restrict__ vt, const float* __restrict__ mbias,
                u16* __restrict__ ohi, u16* __restrict__ olo)
{
    __shared__ u16 Ks[2][64*64];     // [key][d], XOR-swizzled (granule ^ row&7)
    __shared__ u16 Vs[2][64*64];     // [d][key], XOR-swizzled
    const int tid = threadIdx.x;
    const int lane = tid & 63;
    const int w = tid >> 6;          // 0..7
    const int l15 = lane & 15, g = lane >> 4;
    const int g1 = g & 1, gh = g >> 1;
    const int sx = l15 & 7;
    const int bh = blockIdx.y;
    const int b = bh >> 4;
    const int q0 = blockIdx.x * 128;
    const u16* qb = qh + (size_t)bh * S_ * 64;
    const u16* kb = kh + (size_t)bh * S_ * 64;
    const u16* vb = vt + (size_t)bh * 64 * S_;
    const float* mrow = mbias + b * S_;
    const float SCALE2 = 0.18033688011112f;   // 0.125 * log2(e)

    // Q fragments pinned in registers (B-operand: col=q=l15, k=d)
    bf16x8 qf0, qf1;
    {
        const u16* qr = qb + (size_t)(q0 + w*16 + l15) * 64 + g*8;
        qf0 = *(const bf16x8*)qr;
        qf1 = *(const bf16x8*)(qr + 32);
    }
    const f32x4 z4 = {0.f, 0.f, 0.f, 0.f};
    float m_i = 6.0f, l_i = 0.f;     // log2-domain running max; high init = defer
    f32x4 acc[4];                    // O^T: acc[nd][r] = O[q=l15][d=nd*16+g*4+r]
    #pragma unroll
    for (int n = 0; n < 4; n++) acc[n] = z4;

    const int swz = sx << 3;         // u16-index XOR for b128 reads

    auto stage_kv = [&](int bi, int tt) {
        const int kk0 = tt * 64;
        // 512 threads stage one 8KB K-tile + 8KB V-tile in a single pass
        int r = tid >> 3;
        int cs = ((tid & 7) ^ (r & 7)) * 8;
        gld_lds16(kb + (size_t)(kk0 + r) * 64 + cs, (char*)&Ks[bi][0] + ((tid >> 6) << 10));
        gld_lds16(vb + (size_t)r * S_ + kk0 + cs,   (char*)&Vs[bi][0] + ((tid >> 6) << 10));
    };

    stage_kv(0, 0);
    __syncthreads();                             // tile 0 staged + visible

    for (int t = 0; t < S_/64; t++) {
        const int cur = t & 1;
        const int k0 = t * 64;
        // mask bias for THIS tile — issued before stage so its vmcnt wait
        // leaves the prefetch loads in flight (counted wait)
        float4 mb[4];
        #pragma unroll
        for (int nt = 0; nt < 4; nt++)
            mb[nt] = *(const float4*)&mrow[k0 + nt*16 + g*4];
        if (t + 1 < S_/64) stage_kv(cur ^ 1, t + 1);   // issue-ahead (hidden)

        // S^T = K @ Q  (C/D: col=q=l15, row(key)=g*4+r per nt)
        f32x4 sv[4];
        __builtin_amdgcn_s_setprio(1);
        #pragma unroll
        for (int nt = 0; nt < 4; nt++) {
            int row = nt*16 + l15;
            bf16x8 ka0 = *(const bf16x8*)&Ks[cur][(row*64 +  0 + g*8) ^ swz];
            bf16x8 ka1 = *(const bf16x8*)&Ks[cur][(row*64 + 32 + g*8) ^ swz];
            sv[nt] = __builtin_amdgcn_mfma_f32_16x16x32_bf16(ka0, qf0, z4, 0, 0, 0);
            sv[nt] = __builtin_amdgcn_mfma_f32_16x16x32_bf16(ka1, qf1, sv[nt], 0, 0, 0);
        }
        __builtin_amdgcn_s_setprio(0);
        // scale to log2 domain + additive mask bias
        #pragma unroll
        for (int nt = 0; nt < 4; nt++) {
            sv[nt][0] = fmaf(sv[nt][0], SCALE2, mb[nt].x);
            sv[nt][1] = fmaf(sv[nt][1], SCALE2, mb[nt].y);
            sv[nt][2] = fmaf(sv[nt][2], SCALE2, mb[nt].z);
            sv[nt][3] = fmaf(sv[nt][3], SCALE2, mb[nt].w);
        }
        // online softmax (per-lane scalar state, q = l15)
        float rm = fmaxf(fmaxf(sv[0][0], sv[0][1]), fmaxf(sv[0][2], sv[0][3]));
        #pragma unroll
        for (int nt = 1; nt < 4; nt++) {
            rm = fmaxf(rm, fmaxf(sv[nt][0], sv[nt][1]));
            rm = fmaxf(rm, fmaxf(sv[nt][2], sv[nt][3]));
        }
        rm = fmaxf(rm, __shfl_xor(rm, 16, 64));
        rm = fmaxf(rm, __shfl_xor(rm, 32, 64));
        const int grow = __any(rm > m_i);
        float mn = m_i, fsc = 1.f;
        if (grow) {
            mn = fmaxf(m_i, rm);
            fsc = hw_exp2(m_i - mn);
            m_i = mn;
        }
        float rs = 0.f;
        #pragma unroll
        for (int nt = 0; nt < 4; nt++)
            #pragma unroll
            for (int r = 0; r < 4; r++) {
                float p = hw_exp2(sv[nt][r] - mn);
                sv[nt][r] = p;
                rs += p;
            }
        rs += __shfl_xor(rs, 16, 64);
        rs += __shfl_xor(rs, 32, 64);
        if (grow) {
            l_i = l_i * fsc + rs;
            #pragma unroll
            for (int n = 0; n < 4; n++)
                #pragma unroll
                for (int r = 0; r < 4; r++) acc[n][r] *= fsc;
        } else {
            l_i += rs;
        }
        // pack P to bf16x4 fragments — stays in registers
        bf16x4 pk[4];
        #pragma unroll
        for (int nt = 0; nt < 4; nt++) {
            uint2 q2 = make_uint2((u32)cvt_bf(sv[nt][0]) | ((u32)cvt_bf(sv[nt][1]) << 16),
                                  (u32)cvt_bf(sv[nt][2]) | ((u32)cvt_bf(sv[nt][3]) << 16));
            pk[nt] = __builtin_bit_cast(bf16x4, q2);
        }
        // O^T += V^T @ P^T via 16x16x16 (A: row=d, k=key=kk*16+g*4+j from LDS;
        // B: col=q=l15, k=g*4+j = pk[kk] in-register)
        __builtin_amdgcn_s_setprio(1);
        #pragma unroll
        for (int kk = 0; kk < 4; kk++) {
            #pragma unroll
            for (int nd = 0; nd < 4; nd++) {
                int addr = (nd*16 + l15)*64 + ((((kk<<1) + gh) ^ sx) << 3) + g1*4;
                bf16x4 vf = *(const bf16x4*)&Vs[cur][addr];
                acc[nd] = __builtin_amdgcn_mfma_f32_16x16x16bf16_1k(vf, pk[kk], acc[nd], 0, 0, 0);
            }
        }
        __builtin_amdgcn_s_setprio(0);
        __syncthreads();                 // next tile staged+visible; buffers safe
    }
    // epilogue: emit bf16 hi/lo split (A-operand of out-GEMM)
    float inv = l_i > 0.f ? 1.f / l_i : 0.f;
    const int q = q0 + w*16 + l15;
    const size_t rowoff = (size_t)(b * S_ + q) * E_ + (blockIdx.y & 15)*64;
    #pragma unroll
    for (int nd = 0; nd < 4; nd++) {
        #pragma unroll
        for (int r = 0; r < 4; r += 2) {
            float o0 = acc[nd][r]     * inv;
            float o1 = acc[nd][r + 1] * inv;
            u16 h0 = cvt_bf(o0), h1 = cvt_bf(o1);
            u16 lo0 = cvt_bf(o0 - bf2f(h0)), lo1 = cvt_bf(o1 - bf2f(h1));
            int col = nd*16 + g*4 + r;
            *(u32*)&ohi[rowoff + col] = (u32)h0 | ((u32)h1 << 16);
            *(u32*)&olo[rowoff + col] = (u32)lo0 | ((u32)lo1 << 16);
        }
    }
}

// ---------------------------------------------------------------------------
extern "C" void kernel_launch(void* const* d_in, const int* in_sizes, int n_in,
                              void* d_out, int out_size, void* d_ws, size_t ws_size,
                              hipStream_t stream)
{
    (void)in_sizes; (void)n_in; (void)out_size; (void)ws_size;
    const float* x     = (const float*)d_in[0];
    const int*   mask  = (const int*)  d_in[1];
    const float* Wqkv  = (const float*)d_in[2];
    const float* bqkv  = (const float*)d_in[3];
    const float* Wout  = (const float*)d_in[4];
    const float* bout  = (const float*)d_in[5];
    const float* diag  = (const float*)d_in[6];
    const float* alpha = (const float*)d_in[7];
    const float* biash = (const float*)d_in[8];
    float* out = (float*)d_out;

    // Workspace map (bytes). Peak 96.5 MB.
    char* ws = (char*)d_ws;
    float* qkv  = (float*)(ws + 0);            // 50,331,648 (f32 4096x3072)
    u16* wq_hi  = (u16*)(ws + 50331648);       //  6,291,456 (Wqkv^T fp16) } dead after gemm1
    u16* qh     = (u16*)(ws + 50331648);       //  8,388,608 (overlays wq_hi after gemm1)
    u16* khp    = (u16*)(ws + 58720256);       //  8,388,608
    u16* vt     = (u16*)(ws + 67108864);       //  8,388,608
    u16* x_hi   = (u16*)(ws + 75497472);       //  8,388,608 } x fp16 split for gemm1;
    u16* x_lo   = (u16*)(ws + 83886080);       //  8,388,608 } reused as attn bf16 hi/lo
    u16* a_hi   = x_hi;
    u16* a_lo   = x_lo;
    u16* wo_hi  = (u16*)(ws + 92274688);       //  2,097,152 (Wout^T bf16 hi)
    u16* wo_lo  = (u16*)(ws + 94371840);       //  2,097,152
    float* mbias= (float*)(ws + 96468992);     //     16,384 [end 96,485,376]

    // 1) splits + mask bias
    split_a_f16<<<4096, 256, 0, stream>>>(x, x_hi, x_lo, M_ * E_ / 4);
    split_bt_f16hi<<<dim3(N3_/64, E_/64), 256, 0, stream>>>(Wqkv, wq_hi, E_, N3_);
    split_bt<<<dim3(E_/64, E_/64), 256, 0, stream>>>(Wout, wo_hi, wo_lo, E_, E_);
    mask2bias<<<(B_*S_ + 255)/256, 256, 0, stream>>>(mask, mbias, B_*S_);
    // 2) qkv = x @ Wqkv + bqkv  (2-term fp16 MFMA, dbuf pipeline)
    gemm_t<2, true><<<dim3(N3_ / 128, M_ / 128), 256, 0, stream>>>(
        x_hi, x_lo, wq_hi, wq_hi, bqkv, qkv, M_, N3_, E_);
    // 3) FWHT transform, split heads, emit bf16 q,k and v^T
    transform_split<<<(B_ * S_ * H_) / 4, 256, 0, stream>>>(
        qkv, diag, alpha, biash, qh, khp, vt);
    // 4) MFMA flash attention (Q-tile 128, 8 waves; writes bf16 hi/lo split)
    flash_mfma<<<dim3(S_ / 128, B_ * H_), 512, 0, stream>>>(
        qh, khp, vt, mbias, a_hi, a_lo);
    // 5) out = attn @ Wout + bout  (3-term bf16 MFMA, dbuf pipeline)
    gemm_t<3, false><<<dim3(E_ / 128, M_ / 128), 256, 0, stream>>>(
        a_hi, a_lo, wo_hi, wo_lo, bout, out, M_, E_, E_);
}